// Round 3
// baseline (858.904 us; speedup 1.0000x reference)
//
#include <hip/hip_runtime.h>
#include <stdint.h>

#define AS1 __attribute__((address_space(1)))
#define AS3 __attribute__((address_space(3)))

typedef __bf16 bf16;
typedef __bf16 bf16x2 __attribute__((ext_vector_type(2)));
typedef __bf16 bf16x4v __attribute__((ext_vector_type(4)));
typedef __bf16 bf16x8 __attribute__((ext_vector_type(8)));
typedef float f32x4 __attribute__((ext_vector_type(4)));

#define BN_EPS 1e-5f
#define BKT_SHIFT 9              // 512 nodes per bucket
#define BKT_NODES 512
#define TILE_E 8192              // edges per binning block

__device__ __forceinline__ float bf_lo(uint32_t u) {
    union { uint32_t i; float f; } c; c.i = u << 16; return c.f;
}
__device__ __forceinline__ float bf_hi(uint32_t u) {
    union { uint32_t i; float f; } c; c.i = u & 0xffff0000u; return c.f;
}

// ---- convert fp32 -> bf16, 4 elems/thread ----
__global__ void k_cvt_bf16(const float* __restrict__ src, bf16* __restrict__ dst, int n4) {
    int g = blockIdx.x * blockDim.x + threadIdx.x;
    if (g >= n4) return;
    float4 v = ((const float4*)src)[g];
    bf16x4v o; o[0] = (bf16)v.x; o[1] = (bf16)v.y; o[2] = (bf16)v.z; o[3] = (bf16)v.w;
    ((bf16x4v*)dst)[g] = o;
}

// ---- weights -> bf16, transposed to [col][k] for MFMA B-operand staging ----
__global__ void k_prep_w(const float* __restrict__ Wl0, const float* __restrict__ Wr0,
                         const float* __restrict__ Wl1, const float* __restrict__ Wr1,
                         const float* __restrict__ Wl2, const float* __restrict__ Wr2,
                         bf16* __restrict__ Bt0, bf16* __restrict__ Bt1, bf16* __restrict__ Bt2) {
    int idx = blockIdx.x * 256 + threadIdx.x;
    int c = idx >> 8, k = idx & 255;
    float v0 = (k < 128) ? Wl0[k * 128 + c] : Wr0[(k - 128) * 128 + c];
    Bt0[c * 256 + k] = (bf16)v0;
    float v1 = (k < 128) ? Wl1[k * 128 + c] : Wr1[(k - 128) * 128 + c];
    Bt1[c * 256 + k] = (bf16)v1;
    if (k < 128) {
        float v2 = 0.f;
        if (c < 47)      v2 = Wl2[k * 47 + c];
        else if (c < 94) v2 = Wr2[k * 47 + (c - 47)];
        Bt2[c * 128 + k] = (bf16)v2;
    }
}

// ---- CSR build: degree count ----
__global__ void k_count(const int* __restrict__ ei, int* __restrict__ deg, int E) {
    int e = blockIdx.x * blockDim.x + threadIdx.x;
    if (e < E) atomicAdd(&deg[ei[E + e]], 1);
}

// grid-wide scan, stage 1: per-block (1024) inclusive scan + block total
__global__ void k_scan1(const int* __restrict__ deg, int* __restrict__ row_ptr,
                        float* __restrict__ inv_deg, int* __restrict__ partials, int n) {
    __shared__ int wsum[16];
    int tid = threadIdx.x, lane = tid & 63, wid = tid >> 6;
    int i = blockIdx.x * 1024 + tid;
    int d0 = (i < n) ? deg[i] : 0;
    int v = d0;
    #pragma unroll
    for (int d = 1; d < 64; d <<= 1) {
        int t = __shfl_up(v, d, 64);
        if (lane >= d) v += t;
    }
    if (lane == 63) wsum[wid] = v;
    __syncthreads();
    if (tid < 16) {
        int s = wsum[tid];
        #pragma unroll
        for (int d = 1; d < 16; d <<= 1) {
            int t = __shfl_up(s, d, 64);
            if (tid >= d) s += t;
        }
        wsum[tid] = s;
    }
    __syncthreads();
    int incl = v + ((wid > 0) ? wsum[wid - 1] : 0);
    if (i < n) {
        row_ptr[i + 1] = incl;
        inv_deg[i] = 1.0f / (float)(d0 > 1 ? d0 : 1);
    }
    if (tid == 1023) partials[blockIdx.x] = incl;
}

__global__ void k_scan2(int* __restrict__ partials, int nb) {
    __shared__ int wtot[2];
    int t = threadIdx.x;
    int carry = 0;
    for (int base = 0; base < nb; base += 128) {
        int idx = base + t;
        int p = (idx < nb) ? partials[idx] : 0;
        int v = p;
        #pragma unroll
        for (int d = 1; d < 64; d <<= 1) {
            int q = __shfl_up(v, d, 64);
            if ((t & 63) >= d) v += q;
        }
        if ((t & 63) == 63) wtot[t >> 6] = v;
        __syncthreads();
        int add = (t >> 6) ? wtot[0] : 0;
        int incl = v + add + carry;
        if (idx < nb) partials[idx] = incl - p;
        carry += wtot[0] + wtot[1];
        __syncthreads();
    }
}

__global__ void k_scan3(int* __restrict__ row_ptr, const int* __restrict__ partials, int n) {
    int i = blockIdx.x * 1024 + threadIdx.x;
    if (i < n) row_ptr[i + 1] += partials[i >> 10];
    if (i == 0) row_ptr[0] = 0;
}

// ---- binning pass: tile edges -> LDS bucket sort -> contiguous run flush ----
// pair = (src << 9) | (dst & 511); bucket = dst >> 9. Bucket base in pair_buf
// equals row_ptr[bucket * 512] (same slots as col_idx).
__global__ __launch_bounds__(256) void k_bin(const int* __restrict__ ei,
                                             const int* __restrict__ row_ptr,
                                             int* __restrict__ bfill,
                                             uint32_t* __restrict__ pair_buf,
                                             int E, int nbkt) {
    __shared__ uint32_t stage[TILE_E];          // 32 KB
    __shared__ int hist[512], hoff[513], hcur[512];
    const int tid = threadIdx.x;
    const int lane = tid & 63, w = tid >> 6;
    const int e0 = blockIdx.x * TILE_E;

    #pragma unroll
    for (int i = tid; i < 512; i += 256) { hist[i] = 0; }
    __syncthreads();

    // phase A: bucket histogram
    #pragma unroll
    for (int k = 0; k < TILE_E / 256; ++k) {
        int e = e0 + k * 256 + tid;
        if (e < E) {
            int d = ei[E + e];
            atomicAdd(&hist[d >> BKT_SHIFT], 1);
        }
    }
    __syncthreads();

    // scan hist (512 entries) with wave 0
    if (tid < 64) {
        int carry = 0;
        #pragma unroll
        for (int c = 0; c < 8; ++c) {
            int v = hist[c * 64 + lane];
            int incl = v;
            #pragma unroll
            for (int d = 1; d < 64; d <<= 1) {
                int t = __shfl_up(incl, d, 64);
                if (lane >= d) incl += t;
            }
            int excl = carry + incl - v;
            hoff[c * 64 + lane] = excl;
            hcur[c * 64 + lane] = excl;
            carry += __shfl(incl, 63, 64);
        }
        if (lane == 0) hoff[512] = carry;
    }
    __syncthreads();

    // phase B: re-read edges, place into stage at ranked position
    #pragma unroll
    for (int k = 0; k < TILE_E / 256; ++k) {
        int e = e0 + k * 256 + tid;
        if (e < E) {
            int s = ei[e], d = ei[E + e];
            int b = d >> BKT_SHIFT;
            int r = atomicAdd(&hcur[b], 1);
            stage[r] = ((uint32_t)s << BKT_SHIFT) | (uint32_t)(d & (BKT_NODES - 1));
        }
    }
    __syncthreads();

    // flush: per-bucket contiguous run -> global claim
    for (int b = w; b < nbkt; b += 4) {
        int h0 = hoff[b], cnt = hoff[b + 1] - h0;
        if (cnt == 0) continue;
        int g = 0;
        if (lane == 0) g = atomicAdd(&bfill[b], cnt);
        g = __shfl(g, 0, 64);
        int base = row_ptr[b << BKT_SHIFT] + g;
        for (int i = lane; i < cnt; i += 64)
            pair_buf[(size_t)base + i] = stage[h0 + i];
    }
}

// ---- fill pass 2: one block per bucket, localized scatter ----
__global__ __launch_bounds__(256) void k_fill2(const uint32_t* __restrict__ pair_buf,
                                               const int* __restrict__ row_ptr,
                                               int* __restrict__ col_idx, int n, int nbkt) {
    __shared__ int lfil[BKT_NODES];
    const int b = blockIdx.x;
    const int tid = threadIdx.x;
    const int n0 = b << BKT_SHIFT;
    const int n1 = min(n, n0 + BKT_NODES);
    #pragma unroll
    for (int i = tid; i < BKT_NODES; i += 256) lfil[i] = 0;
    __syncthreads();
    const int s = row_ptr[n0], e = row_ptr[n1];
    for (int i = s + tid; i < e; i += 256) {
        uint32_t pk = pair_buf[i];
        int dl = pk & (BKT_NODES - 1);
        int src = pk >> BKT_SHIFT;
        int slot = row_ptr[n0 + dl] + atomicAdd(&lfil[dl], 1);
        col_idx[slot] = src;
    }
}

// ---- mean-aggregate: one wave per node, lane owns 2 features, edge loop x8 ----
__global__ void k_aggregate(const bf16* __restrict__ src, bf16* __restrict__ dst,
                            const int* __restrict__ row_ptr, const int* __restrict__ col_idx,
                            const float* __restrict__ inv_deg, int n) {
    int node = blockIdx.x * 4 + (threadIdx.x >> 6);
    int lane = threadIdx.x & 63;
    if (node >= n) return;
    int e0 = row_ptr[node], e1 = row_ptr[node + 1];
    const bf16* sp = src + (lane << 1);
    float f0 = 0.f, f1 = 0.f;
    int e = e0;
    for (; e + 7 < e1; e += 8) {
        uint32_t u0 = *(const uint32_t*)(sp + (size_t)col_idx[e] * 128);
        uint32_t u1 = *(const uint32_t*)(sp + (size_t)col_idx[e + 1] * 128);
        uint32_t u2 = *(const uint32_t*)(sp + (size_t)col_idx[e + 2] * 128);
        uint32_t u3 = *(const uint32_t*)(sp + (size_t)col_idx[e + 3] * 128);
        uint32_t u4 = *(const uint32_t*)(sp + (size_t)col_idx[e + 4] * 128);
        uint32_t u5 = *(const uint32_t*)(sp + (size_t)col_idx[e + 5] * 128);
        uint32_t u6 = *(const uint32_t*)(sp + (size_t)col_idx[e + 6] * 128);
        uint32_t u7 = *(const uint32_t*)(sp + (size_t)col_idx[e + 7] * 128);
        f0 += ((bf_lo(u0) + bf_lo(u1)) + (bf_lo(u2) + bf_lo(u3))) +
              ((bf_lo(u4) + bf_lo(u5)) + (bf_lo(u6) + bf_lo(u7)));
        f1 += ((bf_hi(u0) + bf_hi(u1)) + (bf_hi(u2) + bf_hi(u3))) +
              ((bf_hi(u4) + bf_hi(u5)) + (bf_hi(u6) + bf_hi(u7)));
    }
    for (; e < e1; ++e) {
        uint32_t u0 = *(const uint32_t*)(sp + (size_t)col_idx[e] * 128);
        f0 += bf_lo(u0);
        f1 += bf_hi(u0);
    }
    float inv = inv_deg[node];
    bf16x2 o; o[0] = (bf16)(f0 * inv); o[1] = (bf16)(f1 * inv);
    *(bf16x2*)(dst + (size_t)node * 128 + (lane << 1)) = o;
}

// ---- MFMA GEMM: out[M x ncols] = [A1|A2] @ Bt^T (+ bias) ----
__global__ __launch_bounds__(256) void k_gemm(
    const bf16* __restrict__ A1, const bf16* __restrict__ A2, const bf16* __restrict__ Bt,
    const float* __restrict__ bias, float* __restrict__ outF, bf16* __restrict__ ylbf,
    int M, int ncols, int ldc, int cps, int chunks, int ldb) {
    __shared__ __attribute__((aligned(16))) bf16 sA[4096];
    __shared__ __attribute__((aligned(16))) bf16 sB[4096];
    const int tid = threadIdx.x;
    const int w = tid >> 6, l = tid & 63;
    const int q = l >> 4, r = l & 15;
    const int r0 = blockIdx.x * 128;
    f32x4 acc[2][8];
    #pragma unroll
    for (int i = 0; i < 2; ++i)
        #pragma unroll
        for (int j = 0; j < 8; ++j) { acc[i][j][0] = 0.f; acc[i][j][1] = 0.f; acc[i][j][2] = 0.f; acc[i][j][3] = 0.f; }

    for (int c = 0; c < chunks; ++c) {
        const bf16* As = (c < cps) ? A1 : A2;
        const int ka = (c < cps ? c : c - cps) * 32;
        __syncthreads();
        #pragma unroll
        for (int i = 0; i < 2; ++i) {
            const int T = w * 2 + i;
            const bf16* ga = As + (size_t)(r0 + T * 16 + r) * 128 + ka + q * 8;
            const bf16* gb = Bt + (T * 16 + r) * ldb + c * 32 + q * 8;
            uint32_t la = (uint32_t)(uintptr_t)(&sA[T * 512]);
            uint32_t lb = (uint32_t)(uintptr_t)(&sB[T * 512]);
            __builtin_amdgcn_global_load_lds((AS1 uint32_t*)(uintptr_t)ga, (AS3 uint32_t*)la, 16, 0, 0);
            __builtin_amdgcn_global_load_lds((AS1 uint32_t*)(uintptr_t)gb, (AS3 uint32_t*)lb, 16, 0, 0);
        }
        __syncthreads();
        bf16x8 af0 = *(const bf16x8*)&sA[(w * 2 + 0) * 512 + q * 128 + r * 8];
        bf16x8 af1 = *(const bf16x8*)&sA[(w * 2 + 1) * 512 + q * 128 + r * 8];
        #pragma unroll
        for (int ct = 0; ct < 8; ++ct) {
            bf16x8 bv = *(const bf16x8*)&sB[ct * 512 + q * 128 + r * 8];
            acc[0][ct] = __builtin_amdgcn_mfma_f32_16x16x32_bf16(af0, bv, acc[0][ct], 0, 0, 0);
            acc[1][ct] = __builtin_amdgcn_mfma_f32_16x16x32_bf16(af1, bv, acc[1][ct], 0, 0, 0);
        }
    }
    if (ylbf == nullptr) {
        #pragma unroll
        for (int rt = 0; rt < 2; ++rt) {
            #pragma unroll
            for (int ct = 0; ct < 8; ++ct) {
                int col = ct * 16 + r;
                if (col >= ncols) continue;
                float bv = bias ? bias[col] : 0.f;
                #pragma unroll
                for (int j = 0; j < 4; ++j) {
                    int row = r0 + w * 32 + rt * 16 + q * 4 + j;
                    if (row < M) outF[(size_t)row * ldc + col] = acc[rt][ct][j] + bv;
                }
            }
        }
    } else {
        #pragma unroll
        for (int rt = 0; rt < 2; ++rt) {
            #pragma unroll
            for (int ct = 0; ct < 8; ++ct) {
                int col = ct * 16 + r;
                #pragma unroll
                for (int j = 0; j < 4; ++j) {
                    int row = r0 + w * 32 + rt * 16 + q * 4 + j;
                    if (row >= M) continue;
                    if (col < 47)      ylbf[(size_t)row * 64 + col] = (bf16)acc[rt][ct][j];
                    else if (col < 94) outF[(size_t)row * 48 + (col - 47)] = acc[rt][ct][j];
                }
            }
        }
    }
}

// ---- BN stats: per-column sum & sumsq ----
__global__ void k_bn_stats(const float* __restrict__ h, float* __restrict__ sums, int n) {
    __shared__ float s1[256], s2[256];
    int t = threadIdx.x;
    int col = t & 127, half = t >> 7;
    int base = blockIdx.x * 128;
    float s = 0.f, q = 0.f;
    for (int i = half; i < 128; i += 2) {
        int row = base + i;
        if (row < n) {
            float v = h[(size_t)row * 128 + col];
            s += v; q += v * v;
        }
    }
    s1[t] = s; s2[t] = q;
    __syncthreads();
    if (t < 128) {
        atomicAdd(&sums[t], s1[t] + s1[t + 128]);
        atomicAdd(&sums[128 + t], s2[t] + s2[t + 128]);
    }
}

// ---- BN apply + ReLU -> bf16 ----
__global__ void k_bn_apply(const float* __restrict__ h, const float* __restrict__ sums,
                           const float* __restrict__ gma, const float* __restrict__ bta,
                           bf16* __restrict__ out, int n) {
    int g = blockIdx.x * blockDim.x + threadIdx.x;
    int row = g >> 6, c2 = g & 63;
    if (row >= n) return;
    int col = c2 << 1;
    float invn = 1.0f / (float)n;
    float mu0 = sums[col] * invn, mu1 = sums[col + 1] * invn;
    float v0 = sums[128 + col] * invn - mu0 * mu0;
    float v1 = sums[128 + col + 1] * invn - mu1 * mu1;
    float sc0 = gma[col] * rsqrtf(v0 + BN_EPS);
    float sc1 = gma[col + 1] * rsqrtf(v1 + BN_EPS);
    float sh0 = bta[col] - mu0 * sc0;
    float sh1 = bta[col + 1] - mu1 * sc1;
    float2 hv = *(const float2*)(h + (size_t)row * 128 + col);
    float r0 = fmaxf(hv.x * sc0 + sh0, 0.f);
    float r1 = fmaxf(hv.y * sc1 + sh1, 0.f);
    bf16x2 o; o[0] = (bf16)r0; o[1] = (bf16)r1;
    *(bf16x2*)(out + (size_t)row * 128 + col) = o;
}

// ---- final: gather-mean of yl (bf16, 64-wide rows) + yr + bl2, log_softmax ----
__global__ void k_final(const bf16* __restrict__ yl, const float* __restrict__ yr,
                        const int* __restrict__ row_ptr, const int* __restrict__ col_idx,
                        const float* __restrict__ inv_deg, const float* __restrict__ bl2,
                        float* __restrict__ out, int n) {
    int node = blockIdx.x * 4 + (threadIdx.x >> 6);
    int c = threadIdx.x & 63;
    if (node >= n) return;
    int e0 = row_ptr[node], e1 = row_ptr[node + 1];
    bool valid = (c < 47);
    const bf16* ylc = yl + c;
    float acc = 0.f;
    int e = e0;
    for (; e + 3 < e1; e += 4) {
        int s0 = col_idx[e], s1 = col_idx[e + 1], s2 = col_idx[e + 2], s3 = col_idx[e + 3];
        float v0 = (float)ylc[(size_t)s0 * 64];
        float v1 = (float)ylc[(size_t)s1 * 64];
        float v2 = (float)ylc[(size_t)s2 * 64];
        float v3 = (float)ylc[(size_t)s3 * 64];
        acc += (v0 + v1) + (v2 + v3);
    }
    for (; e < e1; ++e) acc += (float)ylc[(size_t)col_idx[e] * 64];
    float yv = valid ? yr[(size_t)node * 48 + c] : 0.f;
    float bv = valid ? bl2[c] : 0.f;
    float val = valid ? (acc * inv_deg[node] + yv + bv) : -__builtin_inff();
    float m = val;
    #pragma unroll
    for (int o = 32; o > 0; o >>= 1) m = fmaxf(m, __shfl_xor(m, o, 64));
    float ex = valid ? expf(val - m) : 0.f;
    float sum = ex;
    #pragma unroll
    for (int o = 32; o > 0; o >>= 1) sum += __shfl_xor(sum, o, 64);
    if (valid) out[(size_t)node * 47 + c] = val - m - logf(sum);
}

extern "C" void kernel_launch(void* const* d_in, const int* in_sizes, int n_in,
                              void* d_out, int out_size, void* d_ws, size_t ws_size,
                              hipStream_t stream) {
    const float* x   = (const float*)d_in[0];
    const int*   ei  = (const int*)d_in[1];
    const float* Wl0 = (const float*)d_in[2];
    const float* bl0 = (const float*)d_in[3];
    const float* Wr0 = (const float*)d_in[4];
    const float* g0  = (const float*)d_in[5];
    const float* be0 = (const float*)d_in[6];
    const float* Wl1 = (const float*)d_in[7];
    const float* bl1 = (const float*)d_in[8];
    const float* Wr1 = (const float*)d_in[9];
    const float* g1  = (const float*)d_in[10];
    const float* be1 = (const float*)d_in[11];
    const float* Wl2 = (const float*)d_in[12];
    const float* bl2 = (const float*)d_in[13];
    const float* Wr2 = (const float*)d_in[14];
    float* out = (float*)d_out;

    const int N  = in_sizes[0] / 128;
    const int E  = in_sizes[1] / 2;
    const int NP = ((N + 127) / 128) * 128;
    const int NBKT = (N + BKT_NODES - 1) / BKT_NODES;

    char* p = (char*)d_ws;
    size_t off = 0;
    auto alloc = [&](size_t b) { char* r = p + off; off += (b + 255) & ~(size_t)255; return r; };
    int*   deg     = (int*)alloc((size_t)N * 4);
    int*   row_ptr = (int*)alloc((size_t)(N + 1) * 4);
    float* invd    = (float*)alloc((size_t)N * 4);
    int*   col_idx = (int*)alloc((size_t)E * 4);
    uint32_t* pair_buf = (uint32_t*)alloc((size_t)E * 4);
    int*   bfill   = (int*)alloc(1024 * 4);
    float* bnsum   = (float*)alloc(512 * 4);
    int*   partials= (int*)alloc(1024 * 4);
    bf16*  x_bf    = (bf16*)alloc((size_t)NP * 128 * 2);
    bf16*  aggbf   = (bf16*)alloc((size_t)NP * 128 * 2);
    bf16*  hbf     = (bf16*)alloc((size_t)NP * 128 * 2);
    float* bufF    = (float*)alloc((size_t)NP * 128 * 4);
    bf16*  Bt0     = (bf16*)alloc(128 * 256 * 2);
    bf16*  Bt1     = (bf16*)alloc(128 * 256 * 2);
    bf16*  Bt2     = (bf16*)alloc(128 * 128 * 2);
    bf16*  ylbf = (bf16*)bufF;
    float* yrF  = (float*)((char*)bufF + (size_t)NP * 128);

    hipMemsetAsync(deg, 0, (size_t)N * 4, stream);
    hipMemsetAsync(bfill, 0, 1024 * 4, stream);
    hipMemsetAsync(bnsum, 0, 512 * 4, stream);

    k_prep_w<<<128, 256, 0, stream>>>(Wl0, Wr0, Wl1, Wr1, Wl2, Wr2, Bt0, Bt1, Bt2);
    int n4 = N * 128 / 4;
    k_cvt_bf16<<<(n4 + 255) / 256, 256, 0, stream>>>(x, x_bf, n4);
    k_count<<<(E + 255) / 256, 256, 0, stream>>>(ei, deg, E);
    int nb = (N + 1023) / 1024;
    k_scan1<<<nb, 1024, 0, stream>>>(deg, row_ptr, invd, partials, N);
    k_scan2<<<1, 128, 0, stream>>>(partials, nb);
    k_scan3<<<nb, 1024, 0, stream>>>(row_ptr, partials, N);
    int binBlocks = (E + TILE_E - 1) / TILE_E;
    k_bin<<<binBlocks, 256, 0, stream>>>(ei, row_ptr, bfill, pair_buf, E, NBKT);
    k_fill2<<<NBKT, 256, 0, stream>>>(pair_buf, row_ptr, col_idx, N, NBKT);

    int aggBlocks  = (N + 3) / 4;
    int gemmBlocks = NP / 128;

    // Layer 0
    k_aggregate<<<aggBlocks, 256, 0, stream>>>(x_bf, aggbf, row_ptr, col_idx, invd, N);
    k_gemm<<<gemmBlocks, 256, 0, stream>>>(aggbf, x_bf, Bt0, bl0, bufF, nullptr, N, 128, 128, 4, 8, 256);
    k_bn_stats<<<(N + 127) / 128, 256, 0, stream>>>(bufF, bnsum, N);
    k_bn_apply<<<(N * 64 + 255) / 256, 256, 0, stream>>>(bufF, bnsum, g0, be0, hbf, N);
    // Layer 1
    k_aggregate<<<aggBlocks, 256, 0, stream>>>(hbf, aggbf, row_ptr, col_idx, invd, N);
    k_gemm<<<gemmBlocks, 256, 0, stream>>>(aggbf, hbf, Bt1, bl1, bufF, nullptr, N, 128, 128, 4, 8, 256);
    k_bn_stats<<<(N + 127) / 128, 256, 0, stream>>>(bufF, bnsum + 256, N);
    k_bn_apply<<<(N * 64 + 255) / 256, 256, 0, stream>>>(bufF, bnsum + 256, g1, be1, hbf, N);
    // Layer 2: project to yl (bf16) / yr (fp32), then gather + log_softmax
    k_gemm<<<gemmBlocks, 256, 0, stream>>>(hbf, hbf, Bt2, nullptr, yrF, ylbf, N, 94, 96, 4, 4, 128);
    k_final<<<aggBlocks, 256, 0, stream>>>(ylbf, yrF, row_ptr, col_idx, invd, bl2, out, N);
}

// Round 4
// 703.043 us; speedup vs baseline: 1.2217x; 1.2217x over previous
//
#include <hip/hip_runtime.h>
#include <stdint.h>

#define AS1 __attribute__((address_space(1)))
#define AS3 __attribute__((address_space(3)))

typedef __bf16 bf16;
typedef __bf16 bf16x2 __attribute__((ext_vector_type(2)));
typedef __bf16 bf16x4v __attribute__((ext_vector_type(4)));
typedef __bf16 bf16x8 __attribute__((ext_vector_type(8)));
typedef float f32x4 __attribute__((ext_vector_type(4)));

#define BN_EPS 1e-5f
#define BKT_SHIFT 9              // 512 nodes per bucket
#define BKT_NODES 512
#define TILE_E 4096              // edges per binning block
#define NSLICE 4                 // fill2 blocks per bucket

__device__ __forceinline__ float bf_lo(uint32_t u) {
    union { uint32_t i; float f; } c; c.i = u << 16; return c.f;
}
__device__ __forceinline__ float bf_hi(uint32_t u) {
    union { uint32_t i; float f; } c; c.i = u & 0xffff0000u; return c.f;
}

// ---- convert fp32 -> bf16, 4 elems/thread ----
__global__ void k_cvt_bf16(const float* __restrict__ src, bf16* __restrict__ dst, int n4) {
    int g = blockIdx.x * blockDim.x + threadIdx.x;
    if (g >= n4) return;
    float4 v = ((const float4*)src)[g];
    bf16x4v o; o[0] = (bf16)v.x; o[1] = (bf16)v.y; o[2] = (bf16)v.z; o[3] = (bf16)v.w;
    ((bf16x4v*)dst)[g] = o;
}

// ---- weights -> bf16, transposed to [col][k] for MFMA B-operand staging ----
__global__ void k_prep_w(const float* __restrict__ Wl0, const float* __restrict__ Wr0,
                         const float* __restrict__ Wl1, const float* __restrict__ Wr1,
                         const float* __restrict__ Wl2, const float* __restrict__ Wr2,
                         bf16* __restrict__ Bt0, bf16* __restrict__ Bt1, bf16* __restrict__ Bt2) {
    int idx = blockIdx.x * 256 + threadIdx.x;
    int c = idx >> 8, k = idx & 255;
    float v0 = (k < 128) ? Wl0[k * 128 + c] : Wr0[(k - 128) * 128 + c];
    Bt0[c * 256 + k] = (bf16)v0;
    float v1 = (k < 128) ? Wl1[k * 128 + c] : Wr1[(k - 128) * 128 + c];
    Bt1[c * 256 + k] = (bf16)v1;
    if (k < 128) {
        float v2 = 0.f;
        if (c < 47)      v2 = Wl2[k * 47 + c];
        else if (c < 94) v2 = Wr2[k * 47 + (c - 47)];
        Bt2[c * 128 + k] = (bf16)v2;
    }
}

// ---- CSR build: degree count ----
__global__ void k_count(const int* __restrict__ ei, int* __restrict__ deg, int E) {
    int e = blockIdx.x * blockDim.x + threadIdx.x;
    if (e < E) atomicAdd(&deg[ei[E + e]], 1);
}

// grid-wide scan, stage 1: per-block (1024) inclusive scan + block total
__global__ void k_scan1(const int* __restrict__ deg, int* __restrict__ row_ptr,
                        float* __restrict__ inv_deg, int* __restrict__ partials, int n) {
    __shared__ int wsum[16];
    int tid = threadIdx.x, lane = tid & 63, wid = tid >> 6;
    int i = blockIdx.x * 1024 + tid;
    int d0 = (i < n) ? deg[i] : 0;
    int v = d0;
    #pragma unroll
    for (int d = 1; d < 64; d <<= 1) {
        int t = __shfl_up(v, d, 64);
        if (lane >= d) v += t;
    }
    if (lane == 63) wsum[wid] = v;
    __syncthreads();
    if (tid < 16) {
        int s = wsum[tid];
        #pragma unroll
        for (int d = 1; d < 16; d <<= 1) {
            int t = __shfl_up(s, d, 64);
            if (tid >= d) s += t;
        }
        wsum[tid] = s;
    }
    __syncthreads();
    int incl = v + ((wid > 0) ? wsum[wid - 1] : 0);
    if (i < n) {
        row_ptr[i + 1] = incl;
        inv_deg[i] = 1.0f / (float)(d0 > 1 ? d0 : 1);
    }
    if (tid == 1023) partials[blockIdx.x] = incl;
}

__global__ void k_scan2(int* __restrict__ partials, int nb) {
    __shared__ int wtot[2];
    int t = threadIdx.x;
    int carry = 0;
    for (int base = 0; base < nb; base += 128) {
        int idx = base + t;
        int p = (idx < nb) ? partials[idx] : 0;
        int v = p;
        #pragma unroll
        for (int d = 1; d < 64; d <<= 1) {
            int q = __shfl_up(v, d, 64);
            if ((t & 63) >= d) v += q;
        }
        if ((t & 63) == 63) wtot[t >> 6] = v;
        __syncthreads();
        int add = (t >> 6) ? wtot[0] : 0;
        int incl = v + add + carry;
        if (idx < nb) partials[idx] = incl - p;
        carry += wtot[0] + wtot[1];
        __syncthreads();
    }
}

__global__ void k_scan3(int* __restrict__ row_ptr, const int* __restrict__ partials, int n) {
    int i = blockIdx.x * 1024 + threadIdx.x;
    if (i < n) row_ptr[i + 1] += partials[i >> 10];
    if (i == 0) row_ptr[0] = 0;
}

// ---- binning pass: histogram -> parallel global claim -> direct ranked write ----
// pair = (src << 9) | (dst & 511); bucket = dst >> 9. Bucket base in pair_buf
// equals row_ptr[bucket * 512] (same slot space as col_idx).
__global__ __launch_bounds__(256) void k_bin(const int* __restrict__ ei,
                                             const int* __restrict__ row_ptr,
                                             int* __restrict__ bfill,
                                             uint32_t* __restrict__ pair_buf,
                                             int E, int nbkt) {
    __shared__ int hist[256], gbase[256], hcur[256];
    const int tid = threadIdx.x;
    const int e0 = blockIdx.x * TILE_E;
    hist[tid] = 0;
    __syncthreads();

    int dreg[TILE_E / 256];
    // phase A: bucket histogram (dst cached in registers)
    #pragma unroll
    for (int k = 0; k < TILE_E / 256; ++k) {
        int e = e0 + k * 256 + tid;
        int d = (e < E) ? ei[E + e] : -1;
        dreg[k] = d;
        if (d >= 0) atomicAdd(&hist[d >> BKT_SHIFT], 1);
    }
    __syncthreads();

    // parallel per-bucket global claim (one atomic per non-empty bucket)
    if (tid < nbkt) {
        int h = hist[tid];
        int g = (h > 0) ? atomicAdd(&bfill[tid], h) : 0;
        gbase[tid] = row_ptr[tid << BKT_SHIFT] + g;
        hcur[tid] = 0;
    }
    __syncthreads();

    // phase B: rank within (block,bucket), write pair directly to global
    #pragma unroll
    for (int k = 0; k < TILE_E / 256; ++k) {
        int d = dreg[k];
        if (d >= 0) {
            int e = e0 + k * 256 + tid;
            int s = ei[e];
            int b = d >> BKT_SHIFT;
            int r = atomicAdd(&hcur[b], 1);
            pair_buf[(size_t)gbase[b] + r] =
                ((uint32_t)s << BKT_SHIFT) | (uint32_t)(d & (BKT_NODES - 1));
        }
    }
}

// ---- fill pass 2: NSLICE blocks per bucket, localized scatter, global fil ----
__global__ __launch_bounds__(256) void k_fill2(const uint32_t* __restrict__ pair_buf,
                                               const int* __restrict__ row_ptr,
                                               int* __restrict__ fil,
                                               int* __restrict__ col_idx, int n) {
    const int b = blockIdx.x / NSLICE;
    const int sl = blockIdx.x - b * NSLICE;
    const int n0 = b << BKT_SHIFT;
    const int n1 = min(n, n0 + BKT_NODES);
    const int s = row_ptr[n0], e = row_ptr[n1];
    for (int i = s + sl * 256 + threadIdx.x; i < e; i += 256 * NSLICE) {
        uint32_t pk = pair_buf[i];
        int dl = pk & (BKT_NODES - 1);
        int src = (int)(pk >> BKT_SHIFT);
        int node = n0 + dl;
        int slot = row_ptr[node] + atomicAdd(&fil[node], 1);
        col_idx[slot] = src;
    }
}

// ---- mean-aggregate: one wave per node, lane owns 2 features, edge loop x8 ----
__global__ void k_aggregate(const bf16* __restrict__ src, bf16* __restrict__ dst,
                            const int* __restrict__ row_ptr, const int* __restrict__ col_idx,
                            const float* __restrict__ inv_deg, int n) {
    int node = blockIdx.x * 4 + (threadIdx.x >> 6);
    int lane = threadIdx.x & 63;
    if (node >= n) return;
    int e0 = row_ptr[node], e1 = row_ptr[node + 1];
    const bf16* sp = src + (lane << 1);
    float f0 = 0.f, f1 = 0.f;
    int e = e0;
    for (; e + 7 < e1; e += 8) {
        uint32_t u0 = *(const uint32_t*)(sp + (size_t)col_idx[e] * 128);
        uint32_t u1 = *(const uint32_t*)(sp + (size_t)col_idx[e + 1] * 128);
        uint32_t u2 = *(const uint32_t*)(sp + (size_t)col_idx[e + 2] * 128);
        uint32_t u3 = *(const uint32_t*)(sp + (size_t)col_idx[e + 3] * 128);
        uint32_t u4 = *(const uint32_t*)(sp + (size_t)col_idx[e + 4] * 128);
        uint32_t u5 = *(const uint32_t*)(sp + (size_t)col_idx[e + 5] * 128);
        uint32_t u6 = *(const uint32_t*)(sp + (size_t)col_idx[e + 6] * 128);
        uint32_t u7 = *(const uint32_t*)(sp + (size_t)col_idx[e + 7] * 128);
        f0 += ((bf_lo(u0) + bf_lo(u1)) + (bf_lo(u2) + bf_lo(u3))) +
              ((bf_lo(u4) + bf_lo(u5)) + (bf_lo(u6) + bf_lo(u7)));
        f1 += ((bf_hi(u0) + bf_hi(u1)) + (bf_hi(u2) + bf_hi(u3))) +
              ((bf_hi(u4) + bf_hi(u5)) + (bf_hi(u6) + bf_hi(u7)));
    }
    for (; e < e1; ++e) {
        uint32_t u0 = *(const uint32_t*)(sp + (size_t)col_idx[e] * 128);
        f0 += bf_lo(u0);
        f1 += bf_hi(u0);
    }
    float inv = inv_deg[node];
    bf16x2 o; o[0] = (bf16)(f0 * inv); o[1] = (bf16)(f1 * inv);
    *(bf16x2*)(dst + (size_t)node * 128 + (lane << 1)) = o;
}

// ---- MFMA GEMM: out[M x ncols] = [A1|A2] @ Bt^T (+ bias) ----
__global__ __launch_bounds__(256) void k_gemm(
    const bf16* __restrict__ A1, const bf16* __restrict__ A2, const bf16* __restrict__ Bt,
    const float* __restrict__ bias, float* __restrict__ outF, bf16* __restrict__ ylbf,
    int M, int ncols, int ldc, int cps, int chunks, int ldb) {
    __shared__ __attribute__((aligned(16))) bf16 sA[4096];
    __shared__ __attribute__((aligned(16))) bf16 sB[4096];
    const int tid = threadIdx.x;
    const int w = tid >> 6, l = tid & 63;
    const int q = l >> 4, r = l & 15;
    const int r0 = blockIdx.x * 128;
    f32x4 acc[2][8];
    #pragma unroll
    for (int i = 0; i < 2; ++i)
        #pragma unroll
        for (int j = 0; j < 8; ++j) { acc[i][j][0] = 0.f; acc[i][j][1] = 0.f; acc[i][j][2] = 0.f; acc[i][j][3] = 0.f; }

    for (int c = 0; c < chunks; ++c) {
        const bf16* As = (c < cps) ? A1 : A2;
        const int ka = (c < cps ? c : c - cps) * 32;
        __syncthreads();
        #pragma unroll
        for (int i = 0; i < 2; ++i) {
            const int T = w * 2 + i;
            const bf16* ga = As + (size_t)(r0 + T * 16 + r) * 128 + ka + q * 8;
            const bf16* gb = Bt + (T * 16 + r) * ldb + c * 32 + q * 8;
            uint32_t la = (uint32_t)(uintptr_t)(&sA[T * 512]);
            uint32_t lb = (uint32_t)(uintptr_t)(&sB[T * 512]);
            __builtin_amdgcn_global_load_lds((AS1 uint32_t*)(uintptr_t)ga, (AS3 uint32_t*)la, 16, 0, 0);
            __builtin_amdgcn_global_load_lds((AS1 uint32_t*)(uintptr_t)gb, (AS3 uint32_t*)lb, 16, 0, 0);
        }
        __syncthreads();
        bf16x8 af0 = *(const bf16x8*)&sA[(w * 2 + 0) * 512 + q * 128 + r * 8];
        bf16x8 af1 = *(const bf16x8*)&sA[(w * 2 + 1) * 512 + q * 128 + r * 8];
        #pragma unroll
        for (int ct = 0; ct < 8; ++ct) {
            bf16x8 bv = *(const bf16x8*)&sB[ct * 512 + q * 128 + r * 8];
            acc[0][ct] = __builtin_amdgcn_mfma_f32_16x16x32_bf16(af0, bv, acc[0][ct], 0, 0, 0);
            acc[1][ct] = __builtin_amdgcn_mfma_f32_16x16x32_bf16(af1, bv, acc[1][ct], 0, 0, 0);
        }
    }
    if (ylbf == nullptr) {
        #pragma unroll
        for (int rt = 0; rt < 2; ++rt) {
            #pragma unroll
            for (int ct = 0; ct < 8; ++ct) {
                int col = ct * 16 + r;
                if (col >= ncols) continue;
                float bv = bias ? bias[col] : 0.f;
                #pragma unroll
                for (int j = 0; j < 4; ++j) {
                    int row = r0 + w * 32 + rt * 16 + q * 4 + j;
                    if (row < M) outF[(size_t)row * ldc + col] = acc[rt][ct][j] + bv;
                }
            }
        }
    } else {
        #pragma unroll
        for (int rt = 0; rt < 2; ++rt) {
            #pragma unroll
            for (int ct = 0; ct < 8; ++ct) {
                int col = ct * 16 + r;
                #pragma unroll
                for (int j = 0; j < 4; ++j) {
                    int row = r0 + w * 32 + rt * 16 + q * 4 + j;
                    if (row >= M) continue;
                    if (col < 47)      ylbf[(size_t)row * 64 + col] = (bf16)acc[rt][ct][j];
                    else if (col < 94) outF[(size_t)row * 48 + (col - 47)] = acc[rt][ct][j];
                }
            }
        }
    }
}

// ---- BN stats: per-column sum & sumsq ----
__global__ void k_bn_stats(const float* __restrict__ h, float* __restrict__ sums, int n) {
    __shared__ float s1[256], s2[256];
    int t = threadIdx.x;
    int col = t & 127, half = t >> 7;
    int base = blockIdx.x * 128;
    float s = 0.f, q = 0.f;
    for (int i = half; i < 128; i += 2) {
        int row = base + i;
        if (row < n) {
            float v = h[(size_t)row * 128 + col];
            s += v; q += v * v;
        }
    }
    s1[t] = s; s2[t] = q;
    __syncthreads();
    if (t < 128) {
        atomicAdd(&sums[t], s1[t] + s1[t + 128]);
        atomicAdd(&sums[128 + t], s2[t] + s2[t + 128]);
    }
}

// ---- BN apply + ReLU -> bf16 ----
__global__ void k_bn_apply(const float* __restrict__ h, const float* __restrict__ sums,
                           const float* __restrict__ gma, const float* __restrict__ bta,
                           bf16* __restrict__ out, int n) {
    int g = blockIdx.x * blockDim.x + threadIdx.x;
    int row = g >> 6, c2 = g & 63;
    if (row >= n) return;
    int col = c2 << 1;
    float invn = 1.0f / (float)n;
    float mu0 = sums[col] * invn, mu1 = sums[col + 1] * invn;
    float v0 = sums[128 + col] * invn - mu0 * mu0;
    float v1 = sums[128 + col + 1] * invn - mu1 * mu1;
    float sc0 = gma[col] * rsqrtf(v0 + BN_EPS);
    float sc1 = gma[col + 1] * rsqrtf(v1 + BN_EPS);
    float sh0 = bta[col] - mu0 * sc0;
    float sh1 = bta[col + 1] - mu1 * sc1;
    float2 hv = *(const float2*)(h + (size_t)row * 128 + col);
    float r0 = fmaxf(hv.x * sc0 + sh0, 0.f);
    float r1 = fmaxf(hv.y * sc1 + sh1, 0.f);
    bf16x2 o; o[0] = (bf16)r0; o[1] = (bf16)r1;
    *(bf16x2*)(out + (size_t)row * 128 + col) = o;
}

// ---- final: gather-mean of yl (bf16, 64-wide rows) + yr + bl2, log_softmax ----
__global__ void k_final(const bf16* __restrict__ yl, const float* __restrict__ yr,
                        const int* __restrict__ row_ptr, const int* __restrict__ col_idx,
                        const float* __restrict__ inv_deg, const float* __restrict__ bl2,
                        float* __restrict__ out, int n) {
    int node = blockIdx.x * 4 + (threadIdx.x >> 6);
    int c = threadIdx.x & 63;
    if (node >= n) return;
    int e0 = row_ptr[node], e1 = row_ptr[node + 1];
    bool valid = (c < 47);
    const bf16* ylc = yl + c;
    float acc = 0.f;
    int e = e0;
    for (; e + 3 < e1; e += 4) {
        int s0 = col_idx[e], s1 = col_idx[e + 1], s2 = col_idx[e + 2], s3 = col_idx[e + 3];
        float v0 = (float)ylc[(size_t)s0 * 64];
        float v1 = (float)ylc[(size_t)s1 * 64];
        float v2 = (float)ylc[(size_t)s2 * 64];
        float v3 = (float)ylc[(size_t)s3 * 64];
        acc += (v0 + v1) + (v2 + v3);
    }
    for (; e < e1; ++e) acc += (float)ylc[(size_t)col_idx[e] * 64];
    float yv = valid ? yr[(size_t)node * 48 + c] : 0.f;
    float bv = valid ? bl2[c] : 0.f;
    float val = valid ? (acc * inv_deg[node] + yv + bv) : -__builtin_inff();
    float m = val;
    #pragma unroll
    for (int o = 32; o > 0; o >>= 1) m = fmaxf(m, __shfl_xor(m, o, 64));
    float ex = valid ? expf(val - m) : 0.f;
    float sum = ex;
    #pragma unroll
    for (int o = 32; o > 0; o >>= 1) sum += __shfl_xor(sum, o, 64);
    if (valid) out[(size_t)node * 47 + c] = val - m - logf(sum);
}

extern "C" void kernel_launch(void* const* d_in, const int* in_sizes, int n_in,
                              void* d_out, int out_size, void* d_ws, size_t ws_size,
                              hipStream_t stream) {
    const float* x   = (const float*)d_in[0];
    const int*   ei  = (const int*)d_in[1];
    const float* Wl0 = (const float*)d_in[2];
    const float* bl0 = (const float*)d_in[3];
    const float* Wr0 = (const float*)d_in[4];
    const float* g0  = (const float*)d_in[5];
    const float* be0 = (const float*)d_in[6];
    const float* Wl1 = (const float*)d_in[7];
    const float* bl1 = (const float*)d_in[8];
    const float* Wr1 = (const float*)d_in[9];
    const float* g1  = (const float*)d_in[10];
    const float* be1 = (const float*)d_in[11];
    const float* Wl2 = (const float*)d_in[12];
    const float* bl2 = (const float*)d_in[13];
    const float* Wr2 = (const float*)d_in[14];
    float* out = (float*)d_out;

    const int N  = in_sizes[0] / 128;
    const int E  = in_sizes[1] / 2;
    const int NP = ((N + 127) / 128) * 128;
    const int NBKT = (N + BKT_NODES - 1) / BKT_NODES;

    char* p = (char*)d_ws;
    size_t off = 0;
    auto alloc = [&](size_t b) { char* r = p + off; off += (b + 255) & ~(size_t)255; return r; };
    int*   deg     = (int*)alloc((size_t)N * 4);
    int*   fil     = (int*)alloc((size_t)N * 4);
    int*   row_ptr = (int*)alloc((size_t)(N + 1) * 4);
    float* invd    = (float*)alloc((size_t)N * 4);
    int*   col_idx = (int*)alloc((size_t)E * 4);
    uint32_t* pair_buf = (uint32_t*)alloc((size_t)E * 4);
    int*   bfill   = (int*)alloc(1024 * 4);
    float* bnsum   = (float*)alloc(512 * 4);
    int*   partials= (int*)alloc(1024 * 4);
    bf16*  x_bf    = (bf16*)alloc((size_t)NP * 128 * 2);
    bf16*  aggbf   = (bf16*)alloc((size_t)NP * 128 * 2);
    bf16*  hbf     = (bf16*)alloc((size_t)NP * 128 * 2);
    float* bufF    = (float*)alloc((size_t)NP * 128 * 4);
    bf16*  Bt0     = (bf16*)alloc(128 * 256 * 2);
    bf16*  Bt1     = (bf16*)alloc(128 * 256 * 2);
    bf16*  Bt2     = (bf16*)alloc(128 * 128 * 2);
    bf16*  ylbf = (bf16*)bufF;
    float* yrF  = (float*)((char*)bufF + (size_t)NP * 128);

    hipMemsetAsync(deg, 0, (size_t)N * 4, stream);
    hipMemsetAsync(fil, 0, (size_t)N * 4, stream);
    hipMemsetAsync(bfill, 0, 1024 * 4, stream);
    hipMemsetAsync(bnsum, 0, 512 * 4, stream);

    k_prep_w<<<128, 256, 0, stream>>>(Wl0, Wr0, Wl1, Wr1, Wl2, Wr2, Bt0, Bt1, Bt2);
    int n4 = N * 128 / 4;
    k_cvt_bf16<<<(n4 + 255) / 256, 256, 0, stream>>>(x, x_bf, n4);
    k_count<<<(E + 255) / 256, 256, 0, stream>>>(ei, deg, E);
    int nb = (N + 1023) / 1024;
    k_scan1<<<nb, 1024, 0, stream>>>(deg, row_ptr, invd, partials, N);
    k_scan2<<<1, 128, 0, stream>>>(partials, nb);
    k_scan3<<<nb, 1024, 0, stream>>>(row_ptr, partials, N);
    int binBlocks = (E + TILE_E - 1) / TILE_E;
    k_bin<<<binBlocks, 256, 0, stream>>>(ei, row_ptr, bfill, pair_buf, E, NBKT);
    k_fill2<<<NBKT * NSLICE, 256, 0, stream>>>(pair_buf, row_ptr, fil, col_idx, N);

    int aggBlocks  = (N + 3) / 4;
    int gemmBlocks = NP / 128;

    // Layer 0
    k_aggregate<<<aggBlocks, 256, 0, stream>>>(x_bf, aggbf, row_ptr, col_idx, invd, N);
    k_gemm<<<gemmBlocks, 256, 0, stream>>>(aggbf, x_bf, Bt0, bl0, bufF, nullptr, N, 128, 128, 4, 8, 256);
    k_bn_stats<<<(N + 127) / 128, 256, 0, stream>>>(bufF, bnsum, N);
    k_bn_apply<<<(N * 64 + 255) / 256, 256, 0, stream>>>(bufF, bnsum, g0, be0, hbf, N);
    // Layer 1
    k_aggregate<<<aggBlocks, 256, 0, stream>>>(hbf, aggbf, row_ptr, col_idx, invd, N);
    k_gemm<<<gemmBlocks, 256, 0, stream>>>(aggbf, hbf, Bt1, bl1, bufF, nullptr, N, 128, 128, 4, 8, 256);
    k_bn_stats<<<(N + 127) / 128, 256, 0, stream>>>(bufF, bnsum + 256, N);
    k_bn_apply<<<(N * 64 + 255) / 256, 256, 0, stream>>>(bufF, bnsum + 256, g1, be1, hbf, N);
    // Layer 2: project to yl (bf16) / yr (fp32), then gather + log_softmax
    k_gemm<<<gemmBlocks, 256, 0, stream>>>(hbf, hbf, Bt2, nullptr, yrF, ylbf, N, 94, 96, 4, 4, 128);
    k_final<<<aggBlocks, 256, 0, stream>>>(ylbf, yrF, row_ptr, col_idx, invd, bl2, out, N);
}

// Round 5
// 682.828 us; speedup vs baseline: 1.2579x; 1.0296x over previous
//
#include <hip/hip_runtime.h>
#include <stdint.h>

#define AS1 __attribute__((address_space(1)))
#define AS3 __attribute__((address_space(3)))

typedef __bf16 bf16;
typedef __bf16 bf16x2 __attribute__((ext_vector_type(2)));
typedef __bf16 bf16x4v __attribute__((ext_vector_type(4)));
typedef __bf16 bf16x8 __attribute__((ext_vector_type(8)));
typedef float f32x4 __attribute__((ext_vector_type(4)));

#define BN_EPS 1e-5f
#define BKT_SHIFT 9              // 512 nodes per bucket
#define BKT_NODES 512
#define TILE_E 2048              // edges per binning block
#define NSLICE 4                 // fill2 blocks per bucket

__device__ __forceinline__ float bf_lo(uint32_t u) {
    union { uint32_t i; float f; } c; c.i = u << 16; return c.f;
}
__device__ __forceinline__ float bf_hi(uint32_t u) {
    union { uint32_t i; float f; } c; c.i = u & 0xffff0000u; return c.f;
}

// ---- convert fp32 -> bf16, 4 elems/thread ----
__global__ void k_cvt_bf16(const float* __restrict__ src, bf16* __restrict__ dst, int n4) {
    int g = blockIdx.x * blockDim.x + threadIdx.x;
    if (g >= n4) return;
    float4 v = ((const float4*)src)[g];
    bf16x4v o; o[0] = (bf16)v.x; o[1] = (bf16)v.y; o[2] = (bf16)v.z; o[3] = (bf16)v.w;
    ((bf16x4v*)dst)[g] = o;
}

// ---- weights -> bf16, transposed to [col][k] for MFMA B-operand staging ----
__global__ void k_prep_w(const float* __restrict__ Wl0, const float* __restrict__ Wr0,
                         const float* __restrict__ Wl1, const float* __restrict__ Wr1,
                         const float* __restrict__ Wl2, const float* __restrict__ Wr2,
                         bf16* __restrict__ Bt0, bf16* __restrict__ Bt1, bf16* __restrict__ Bt2) {
    int idx = blockIdx.x * 256 + threadIdx.x;
    int c = idx >> 8, k = idx & 255;
    float v0 = (k < 128) ? Wl0[k * 128 + c] : Wr0[(k - 128) * 128 + c];
    Bt0[c * 256 + k] = (bf16)v0;
    float v1 = (k < 128) ? Wl1[k * 128 + c] : Wr1[(k - 128) * 128 + c];
    Bt1[c * 256 + k] = (bf16)v1;
    if (k < 128) {
        float v2 = 0.f;
        if (c < 47)      v2 = Wl2[k * 47 + c];
        else if (c < 94) v2 = Wr2[k * 47 + (c - 47)];
        Bt2[c * 128 + k] = (bf16)v2;
    }
}

// ---- CSR build: degree count ----
__global__ void k_count(const int* __restrict__ ei, int* __restrict__ deg, int E) {
    int e = blockIdx.x * blockDim.x + threadIdx.x;
    if (e < E) atomicAdd(&deg[ei[E + e]], 1);
}

// grid-wide scan, stage 1: per-block (1024) inclusive scan + block total
__global__ void k_scan1(const int* __restrict__ deg, int* __restrict__ row_ptr,
                        float* __restrict__ inv_deg, int* __restrict__ partials, int n) {
    __shared__ int wsum[16];
    int tid = threadIdx.x, lane = tid & 63, wid = tid >> 6;
    int i = blockIdx.x * 1024 + tid;
    int d0 = (i < n) ? deg[i] : 0;
    int v = d0;
    #pragma unroll
    for (int d = 1; d < 64; d <<= 1) {
        int t = __shfl_up(v, d, 64);
        if (lane >= d) v += t;
    }
    if (lane == 63) wsum[wid] = v;
    __syncthreads();
    if (tid < 16) {
        int s = wsum[tid];
        #pragma unroll
        for (int d = 1; d < 16; d <<= 1) {
            int t = __shfl_up(s, d, 64);
            if (tid >= d) s += t;
        }
        wsum[tid] = s;
    }
    __syncthreads();
    int incl = v + ((wid > 0) ? wsum[wid - 1] : 0);
    if (i < n) {
        row_ptr[i + 1] = incl;
        inv_deg[i] = 1.0f / (float)(d0 > 1 ? d0 : 1);
    }
    if (tid == 1023) partials[blockIdx.x] = incl;
}

__global__ void k_scan2(int* __restrict__ partials, int nb) {
    __shared__ int wtot[2];
    int t = threadIdx.x;
    int carry = 0;
    for (int base = 0; base < nb; base += 128) {
        int idx = base + t;
        int p = (idx < nb) ? partials[idx] : 0;
        int v = p;
        #pragma unroll
        for (int d = 1; d < 64; d <<= 1) {
            int q = __shfl_up(v, d, 64);
            if ((t & 63) >= d) v += q;
        }
        if ((t & 63) == 63) wtot[t >> 6] = v;
        __syncthreads();
        int add = (t >> 6) ? wtot[0] : 0;
        int incl = v + add + carry;
        if (idx < nb) partials[idx] = incl - p;
        carry += wtot[0] + wtot[1];
        __syncthreads();
    }
}

__global__ void k_scan3(int* __restrict__ row_ptr, const int* __restrict__ partials, int n) {
    int i = blockIdx.x * 1024 + threadIdx.x;
    if (i < n) row_ptr[i + 1] += partials[i >> 10];
    if (i == 0) row_ptr[0] = 0;
}

// ---- binning pass: histogram -> parallel global claim -> direct ranked write ----
__global__ __launch_bounds__(256) void k_bin(const int* __restrict__ ei,
                                             const int* __restrict__ row_ptr,
                                             int* __restrict__ bfill,
                                             uint32_t* __restrict__ pair_buf,
                                             int E, int nbkt) {
    __shared__ int hist[256], gbase[256], hcur[256];
    const int tid = threadIdx.x;
    const int e0 = blockIdx.x * TILE_E;
    hist[tid] = 0;
    __syncthreads();

    int dreg[TILE_E / 256];
    #pragma unroll
    for (int k = 0; k < TILE_E / 256; ++k) {
        int e = e0 + k * 256 + tid;
        int d = (e < E) ? ei[E + e] : -1;
        dreg[k] = d;
        if (d >= 0) atomicAdd(&hist[d >> BKT_SHIFT], 1);
    }
    __syncthreads();

    if (tid < nbkt) {
        int h = hist[tid];
        int g = (h > 0) ? atomicAdd(&bfill[tid], h) : 0;
        gbase[tid] = row_ptr[tid << BKT_SHIFT] + g;
        hcur[tid] = 0;
    }
    __syncthreads();

    #pragma unroll
    for (int k = 0; k < TILE_E / 256; ++k) {
        int d = dreg[k];
        if (d >= 0) {
            int e = e0 + k * 256 + tid;
            int s = ei[e];
            int b = d >> BKT_SHIFT;
            int r = atomicAdd(&hcur[b], 1);
            pair_buf[(size_t)gbase[b] + r] =
                ((uint32_t)s << BKT_SHIFT) | (uint32_t)(d & (BKT_NODES - 1));
        }
    }
}

// ---- fill pass 2: NSLICE blocks per bucket, localized scatter, global fil ----
__global__ __launch_bounds__(256) void k_fill2(const uint32_t* __restrict__ pair_buf,
                                               const int* __restrict__ row_ptr,
                                               int* __restrict__ fil,
                                               int* __restrict__ col_idx, int n) {
    const int b = blockIdx.x / NSLICE;
    const int sl = blockIdx.x - b * NSLICE;
    const int n0 = b << BKT_SHIFT;
    const int n1 = min(n, n0 + BKT_NODES);
    const int s = row_ptr[n0], e = row_ptr[n1];
    for (int i = s + sl * 256 + threadIdx.x; i < e; i += 256 * NSLICE) {
        uint32_t pk = pair_buf[i];
        int dl = pk & (BKT_NODES - 1);
        int src = (int)(pk >> BKT_SHIFT);
        int node = n0 + dl;
        int slot = row_ptr[node] + atomicAdd(&fil[node], 1);
        col_idx[slot] = src;
    }
}

// ---- mean-aggregate: one wave per node, lane owns 2 features, edge loop x8 ----
__global__ void k_aggregate(const bf16* __restrict__ src, bf16* __restrict__ dst,
                            const int* __restrict__ row_ptr, const int* __restrict__ col_idx,
                            const float* __restrict__ inv_deg, int n) {
    int node = blockIdx.x * 4 + (threadIdx.x >> 6);
    int lane = threadIdx.x & 63;
    if (node >= n) return;
    int e0 = row_ptr[node], e1 = row_ptr[node + 1];
    const bf16* sp = src + (lane << 1);
    float f0 = 0.f, f1 = 0.f;
    int e = e0;
    for (; e + 7 < e1; e += 8) {
        uint32_t u0 = *(const uint32_t*)(sp + (size_t)col_idx[e] * 128);
        uint32_t u1 = *(const uint32_t*)(sp + (size_t)col_idx[e + 1] * 128);
        uint32_t u2 = *(const uint32_t*)(sp + (size_t)col_idx[e + 2] * 128);
        uint32_t u3 = *(const uint32_t*)(sp + (size_t)col_idx[e + 3] * 128);
        uint32_t u4 = *(const uint32_t*)(sp + (size_t)col_idx[e + 4] * 128);
        uint32_t u5 = *(const uint32_t*)(sp + (size_t)col_idx[e + 5] * 128);
        uint32_t u6 = *(const uint32_t*)(sp + (size_t)col_idx[e + 6] * 128);
        uint32_t u7 = *(const uint32_t*)(sp + (size_t)col_idx[e + 7] * 128);
        f0 += ((bf_lo(u0) + bf_lo(u1)) + (bf_lo(u2) + bf_lo(u3))) +
              ((bf_lo(u4) + bf_lo(u5)) + (bf_lo(u6) + bf_lo(u7)));
        f1 += ((bf_hi(u0) + bf_hi(u1)) + (bf_hi(u2) + bf_hi(u3))) +
              ((bf_hi(u4) + bf_hi(u5)) + (bf_hi(u6) + bf_hi(u7)));
    }
    for (; e < e1; ++e) {
        uint32_t u0 = *(const uint32_t*)(sp + (size_t)col_idx[e] * 128);
        f0 += bf_lo(u0);
        f1 += bf_hi(u0);
    }
    float inv = inv_deg[node];
    bf16x2 o; o[0] = (bf16)(f0 * inv); o[1] = (bf16)(f1 * inv);
    *(bf16x2*)(dst + (size_t)node * 128 + (lane << 1)) = o;
}

// ---- MFMA GEMM: out[M x ncols] = [A1|A2] @ Bt^T (+ bias), fused BN stats ----
// mode 0 (ylbf==nullptr): fp32 out + bias; if stats, atomically accumulate
//   per-column sum/sumsq into stats[0:128]/stats[128:256].
// mode 1: cols 0..46 -> ylbf (bf16, row stride 47); 47..93 -> outF (fp32, stride 48).
__global__ __launch_bounds__(256) void k_gemm(
    const bf16* __restrict__ A1, const bf16* __restrict__ A2, const bf16* __restrict__ Bt,
    const float* __restrict__ bias, float* __restrict__ outF, bf16* __restrict__ ylbf,
    float* __restrict__ stats,
    int M, int ncols, int ldc, int cps, int chunks, int ldb) {
    __shared__ __attribute__((aligned(16))) bf16 sA[4096];
    __shared__ __attribute__((aligned(16))) bf16 sB[4096];
    __shared__ float scol[128], scol2[128];
    const int tid = threadIdx.x;
    const int w = tid >> 6, l = tid & 63;
    const int q = l >> 4, r = l & 15;
    const int r0 = blockIdx.x * 128;
    if (tid < 128) { scol[tid] = 0.f; scol2[tid] = 0.f; }
    f32x4 acc[2][8];
    #pragma unroll
    for (int i = 0; i < 2; ++i)
        #pragma unroll
        for (int j = 0; j < 8; ++j) { acc[i][j][0] = 0.f; acc[i][j][1] = 0.f; acc[i][j][2] = 0.f; acc[i][j][3] = 0.f; }

    for (int c = 0; c < chunks; ++c) {
        const bf16* As = (c < cps) ? A1 : A2;
        const int ka = (c < cps ? c : c - cps) * 32;
        __syncthreads();
        #pragma unroll
        for (int i = 0; i < 2; ++i) {
            const int T = w * 2 + i;
            const bf16* ga = As + (size_t)(r0 + T * 16 + r) * 128 + ka + q * 8;
            const bf16* gb = Bt + (T * 16 + r) * ldb + c * 32 + q * 8;
            uint32_t la = (uint32_t)(uintptr_t)(&sA[T * 512]);
            uint32_t lb = (uint32_t)(uintptr_t)(&sB[T * 512]);
            __builtin_amdgcn_global_load_lds((AS1 uint32_t*)(uintptr_t)ga, (AS3 uint32_t*)la, 16, 0, 0);
            __builtin_amdgcn_global_load_lds((AS1 uint32_t*)(uintptr_t)gb, (AS3 uint32_t*)lb, 16, 0, 0);
        }
        __syncthreads();
        bf16x8 af0 = *(const bf16x8*)&sA[(w * 2 + 0) * 512 + q * 128 + r * 8];
        bf16x8 af1 = *(const bf16x8*)&sA[(w * 2 + 1) * 512 + q * 128 + r * 8];
        #pragma unroll
        for (int ct = 0; ct < 8; ++ct) {
            bf16x8 bv = *(const bf16x8*)&sB[ct * 512 + q * 128 + r * 8];
            acc[0][ct] = __builtin_amdgcn_mfma_f32_16x16x32_bf16(af0, bv, acc[0][ct], 0, 0, 0);
            acc[1][ct] = __builtin_amdgcn_mfma_f32_16x16x32_bf16(af1, bv, acc[1][ct], 0, 0, 0);
        }
    }
    if (ylbf == nullptr) {
        #pragma unroll
        for (int ct = 0; ct < 8; ++ct) {
            int col = ct * 16 + r;
            float bv = bias ? bias[col] : 0.f;
            float s_c = 0.f, q_c = 0.f;
            #pragma unroll
            for (int rt = 0; rt < 2; ++rt) {
                #pragma unroll
                for (int j = 0; j < 4; ++j) {
                    int row = r0 + w * 32 + rt * 16 + q * 4 + j;
                    if (row < M) {
                        float v = acc[rt][ct][j] + bv;
                        outF[(size_t)row * ldc + col] = v;
                        s_c += v; q_c += v * v;
                    }
                }
            }
            if (stats) {
                atomicAdd(&scol[col], s_c);
                atomicAdd(&scol2[col], q_c);
            }
        }
        if (stats) {
            __syncthreads();
            if (tid < 128) {
                atomicAdd(&stats[tid], scol[tid]);
                atomicAdd(&stats[128 + tid], scol2[tid]);
            }
        }
    } else {
        #pragma unroll
        for (int rt = 0; rt < 2; ++rt) {
            #pragma unroll
            for (int ct = 0; ct < 8; ++ct) {
                int col = ct * 16 + r;
                #pragma unroll
                for (int j = 0; j < 4; ++j) {
                    int row = r0 + w * 32 + rt * 16 + q * 4 + j;
                    if (row >= M) continue;
                    if (col < 47)      ylbf[(size_t)row * 47 + col] = (bf16)acc[rt][ct][j];
                    else if (col < 94) outF[(size_t)row * 48 + (col - 47)] = acc[rt][ct][j];
                }
            }
        }
    }
}

// ---- BN apply + ReLU -> bf16 ----
__global__ void k_bn_apply(const float* __restrict__ h, const float* __restrict__ sums,
                           const float* __restrict__ gma, const float* __restrict__ bta,
                           bf16* __restrict__ out, int n) {
    int g = blockIdx.x * blockDim.x + threadIdx.x;
    int row = g >> 6, c2 = g & 63;
    if (row >= n) return;
    int col = c2 << 1;
    float invn = 1.0f / (float)n;
    float mu0 = sums[col] * invn, mu1 = sums[col + 1] * invn;
    float v0 = sums[128 + col] * invn - mu0 * mu0;
    float v1 = sums[128 + col + 1] * invn - mu1 * mu1;
    float sc0 = gma[col] * rsqrtf(v0 + BN_EPS);
    float sc1 = gma[col + 1] * rsqrtf(v1 + BN_EPS);
    float sh0 = bta[col] - mu0 * sc0;
    float sh1 = bta[col + 1] - mu1 * sc1;
    float2 hv = *(const float2*)(h + (size_t)row * 128 + col);
    float r0 = fmaxf(hv.x * sc0 + sh0, 0.f);
    float r1 = fmaxf(hv.y * sc1 + sh1, 0.f);
    bf16x2 o; o[0] = (bf16)r0; o[1] = (bf16)r1;
    *(bf16x2*)(out + (size_t)row * 128 + col) = o;
}

// ---- final: gather-mean of yl (bf16, packed stride 47) + yr + bl2, log_softmax ----
__global__ void k_final(const bf16* __restrict__ yl, const float* __restrict__ yr,
                        const int* __restrict__ row_ptr, const int* __restrict__ col_idx,
                        const float* __restrict__ inv_deg, const float* __restrict__ bl2,
                        float* __restrict__ out, int n) {
    int node = blockIdx.x * 4 + (threadIdx.x >> 6);
    int c = threadIdx.x & 63;
    if (node >= n) return;
    int e0 = row_ptr[node], e1 = row_ptr[node + 1];
    bool valid = (c < 47);
    int cc = valid ? c : 0;
    const bf16* ylc = yl + cc;
    float acc = 0.f;
    int e = e0;
    for (; e + 7 < e1; e += 8) {
        float v0 = (float)ylc[(size_t)col_idx[e] * 47];
        float v1 = (float)ylc[(size_t)col_idx[e + 1] * 47];
        float v2 = (float)ylc[(size_t)col_idx[e + 2] * 47];
        float v3 = (float)ylc[(size_t)col_idx[e + 3] * 47];
        float v4 = (float)ylc[(size_t)col_idx[e + 4] * 47];
        float v5 = (float)ylc[(size_t)col_idx[e + 5] * 47];
        float v6 = (float)ylc[(size_t)col_idx[e + 6] * 47];
        float v7 = (float)ylc[(size_t)col_idx[e + 7] * 47];
        acc += ((v0 + v1) + (v2 + v3)) + ((v4 + v5) + (v6 + v7));
    }
    for (; e < e1; ++e) acc += (float)ylc[(size_t)col_idx[e] * 47];
    float yv = valid ? yr[(size_t)node * 48 + c] : 0.f;
    float bv = valid ? bl2[c] : 0.f;
    float val = valid ? (acc * inv_deg[node] + yv + bv) : -__builtin_inff();
    float m = val;
    #pragma unroll
    for (int o = 32; o > 0; o >>= 1) m = fmaxf(m, __shfl_xor(m, o, 64));
    float ex = valid ? expf(val - m) : 0.f;
    float sum = ex;
    #pragma unroll
    for (int o = 32; o > 0; o >>= 1) sum += __shfl_xor(sum, o, 64);
    if (valid) out[(size_t)node * 47 + c] = val - m - logf(sum);
}

extern "C" void kernel_launch(void* const* d_in, const int* in_sizes, int n_in,
                              void* d_out, int out_size, void* d_ws, size_t ws_size,
                              hipStream_t stream) {
    const float* x   = (const float*)d_in[0];
    const int*   ei  = (const int*)d_in[1];
    const float* Wl0 = (const float*)d_in[2];
    const float* bl0 = (const float*)d_in[3];
    const float* Wr0 = (const float*)d_in[4];
    const float* g0  = (const float*)d_in[5];
    const float* be0 = (const float*)d_in[6];
    const float* Wl1 = (const float*)d_in[7];
    const float* bl1 = (const float*)d_in[8];
    const float* Wr1 = (const float*)d_in[9];
    const float* g1  = (const float*)d_in[10];
    const float* be1 = (const float*)d_in[11];
    const float* Wl2 = (const float*)d_in[12];
    const float* bl2 = (const float*)d_in[13];
    const float* Wr2 = (const float*)d_in[14];
    float* out = (float*)d_out;

    const int N  = in_sizes[0] / 128;
    const int E  = in_sizes[1] / 2;
    const int NP = ((N + 127) / 128) * 128;
    const int NBKT = (N + BKT_NODES - 1) / BKT_NODES;

    char* p = (char*)d_ws;
    size_t off = 0;
    auto alloc = [&](size_t b) { char* r = p + off; off += (b + 255) & ~(size_t)255; return r; };
    // zero-init region (one memset): deg, fil, bfill, bnsum
    int*   deg     = (int*)alloc((size_t)N * 4);
    int*   fil     = (int*)alloc((size_t)N * 4);
    int*   bfill   = (int*)alloc(1024 * 4);
    float* bnsum   = (float*)alloc(512 * 4);
    size_t zero_span = off;
    int*   row_ptr = (int*)alloc((size_t)(N + 1) * 4);
    float* invd    = (float*)alloc((size_t)N * 4);
    int*   col_idx = (int*)alloc((size_t)E * 4);
    uint32_t* pair_buf = (uint32_t*)alloc((size_t)E * 4);
    int*   partials= (int*)alloc(1024 * 4);
    bf16*  x_bf    = (bf16*)alloc((size_t)NP * 128 * 2);
    bf16*  aggbf   = (bf16*)alloc((size_t)NP * 128 * 2);
    bf16*  hbf     = (bf16*)alloc((size_t)NP * 128 * 2);
    float* bufF    = (float*)alloc((size_t)NP * 128 * 4 + 256);
    bf16*  Bt0     = (bf16*)alloc(128 * 256 * 2);
    bf16*  Bt1     = (bf16*)alloc(128 * 256 * 2);
    bf16*  Bt2     = (bf16*)alloc(128 * 128 * 2);
    // layer-2 outputs alias bufF (free by then): yl bf16 [N][47] packed, yr fp32 [NP][48]
    bf16*  ylbf = (bf16*)bufF;
    float* yrF  = (float*)((char*)bufF + (((size_t)N * 47 * 2 + 255) & ~(size_t)255));

    hipMemsetAsync(deg, 0, zero_span, stream);

    k_prep_w<<<128, 256, 0, stream>>>(Wl0, Wr0, Wl1, Wr1, Wl2, Wr2, Bt0, Bt1, Bt2);
    int n4 = N * 128 / 4;
    k_cvt_bf16<<<(n4 + 255) / 256, 256, 0, stream>>>(x, x_bf, n4);
    k_count<<<(E + 255) / 256, 256, 0, stream>>>(ei, deg, E);
    int nb = (N + 1023) / 1024;
    k_scan1<<<nb, 1024, 0, stream>>>(deg, row_ptr, invd, partials, N);
    k_scan2<<<1, 128, 0, stream>>>(partials, nb);
    k_scan3<<<nb, 1024, 0, stream>>>(row_ptr, partials, N);
    int binBlocks = (E + TILE_E - 1) / TILE_E;
    k_bin<<<binBlocks, 256, 0, stream>>>(ei, row_ptr, bfill, pair_buf, E, NBKT);
    k_fill2<<<NBKT * NSLICE, 256, 0, stream>>>(pair_buf, row_ptr, fil, col_idx, N);

    int aggBlocks  = (N + 3) / 4;
    int gemmBlocks = NP / 128;

    // Layer 0
    k_aggregate<<<aggBlocks, 256, 0, stream>>>(x_bf, aggbf, row_ptr, col_idx, invd, N);
    k_gemm<<<gemmBlocks, 256, 0, stream>>>(aggbf, x_bf, Bt0, bl0, bufF, nullptr, bnsum, N, 128, 128, 4, 8, 256);
    k_bn_apply<<<(N * 64 + 255) / 256, 256, 0, stream>>>(bufF, bnsum, g0, be0, hbf, N);
    // Layer 1
    k_aggregate<<<aggBlocks, 256, 0, stream>>>(hbf, aggbf, row_ptr, col_idx, invd, N);
    k_gemm<<<gemmBlocks, 256, 0, stream>>>(aggbf, hbf, Bt1, bl1, bufF, nullptr, bnsum + 256, N, 128, 128, 4, 8, 256);
    k_bn_apply<<<(N * 64 + 255) / 256, 256, 0, stream>>>(bufF, bnsum + 256, g1, be1, hbf, N);
    // Layer 2: project to yl (bf16, packed 47) / yr (fp32), then gather + log_softmax
    k_gemm<<<gemmBlocks, 256, 0, stream>>>(hbf, hbf, Bt2, nullptr, yrF, ylbf, nullptr, N, 94, 96, 4, 4, 128);
    k_final<<<aggBlocks, 256, 0, stream>>>(ylbf, yrF, row_ptr, col_idx, invd, bl2, out, N);
}

// Round 6
// 664.094 us; speedup vs baseline: 1.2933x; 1.0282x over previous
//
#include <hip/hip_runtime.h>
#include <hip/hip_fp8.h>
#include <stdint.h>

#define AS1 __attribute__((address_space(1)))
#define AS3 __attribute__((address_space(3)))

typedef __bf16 bf16;
typedef __bf16 bf16x2 __attribute__((ext_vector_type(2)));
typedef __bf16 bf16x4v __attribute__((ext_vector_type(4)));
typedef __bf16 bf16x8 __attribute__((ext_vector_type(8)));
typedef float f32x4 __attribute__((ext_vector_type(4)));
typedef __hip_fp8_e4m3 fp8;

#define BN_EPS 1e-5f
#define BKT_SHIFT 9              // 512 nodes per bucket
#define BKT_NODES 512
#define TILE_E 2048              // edges per binning block
#define NSLICE 4                 // fill2 blocks per bucket

__device__ __forceinline__ float bf_lo(uint32_t u) {
    union { uint32_t i; float f; } c; c.i = u << 16; return c.f;
}
__device__ __forceinline__ float bf_hi(uint32_t u) {
    union { uint32_t i; float f; } c; c.i = u & 0xffff0000u; return c.f;
}

// ---- fused setup: weight transpose+cvt, x fp32->bf16, degree count ----
__global__ void k_setup(const float* __restrict__ x, bf16* __restrict__ x_bf, int n4,
                        const int* __restrict__ ei, int* __restrict__ deg, int E,
                        const float* __restrict__ Wl0, const float* __restrict__ Wr0,
                        const float* __restrict__ Wl1, const float* __restrict__ Wr1,
                        const float* __restrict__ Wl2, const float* __restrict__ Wr2,
                        bf16* __restrict__ Bt0, bf16* __restrict__ Bt1, bf16* __restrict__ Bt2) {
    int g = blockIdx.x * 256 + threadIdx.x;
    if (g < n4) {
        float4 v = ((const float4*)x)[g];
        bf16x4v o; o[0] = (bf16)v.x; o[1] = (bf16)v.y; o[2] = (bf16)v.z; o[3] = (bf16)v.w;
        ((bf16x4v*)x_bf)[g] = o;
    }
    if (g < E) atomicAdd(&deg[ei[E + g]], 1);
    if (blockIdx.x < 128) {
        int idx = g;                 // 32768 threads: c in [0,128), k in [0,256)
        int c = idx >> 8, k = idx & 255;
        float v0 = (k < 128) ? Wl0[k * 128 + c] : Wr0[(k - 128) * 128 + c];
        Bt0[c * 256 + k] = (bf16)v0;
        float v1 = (k < 128) ? Wl1[k * 128 + c] : Wr1[(k - 128) * 128 + c];
        Bt1[c * 256 + k] = (bf16)v1;
        if (k < 128) {
            float v2 = 0.f;
            if (c < 47)      v2 = Wl2[k * 47 + c];
            else if (c < 94) v2 = Wr2[k * 47 + (c - 47)];
            Bt2[c * 128 + k] = (bf16)v2;
        }
    }
}

// grid-wide scan, stage 1: per-block (1024) inclusive scan + block total
__global__ void k_scan1(const int* __restrict__ deg, int* __restrict__ row_ptr,
                        float* __restrict__ inv_deg, int* __restrict__ partials, int n) {
    __shared__ int wsum[16];
    int tid = threadIdx.x, lane = tid & 63, wid = tid >> 6;
    int i = blockIdx.x * 1024 + tid;
    int d0 = (i < n) ? deg[i] : 0;
    int v = d0;
    #pragma unroll
    for (int d = 1; d < 64; d <<= 1) {
        int t = __shfl_up(v, d, 64);
        if (lane >= d) v += t;
    }
    if (lane == 63) wsum[wid] = v;
    __syncthreads();
    if (tid < 16) {
        int s = wsum[tid];
        #pragma unroll
        for (int d = 1; d < 16; d <<= 1) {
            int t = __shfl_up(s, d, 64);
            if (tid >= d) s += t;
        }
        wsum[tid] = s;
    }
    __syncthreads();
    int incl = v + ((wid > 0) ? wsum[wid - 1] : 0);
    if (i < n) {
        row_ptr[i + 1] = incl;
        inv_deg[i] = 1.0f / (float)(d0 > 1 ? d0 : 1);
    }
    if (tid == 1023) partials[blockIdx.x] = incl;
}

__global__ void k_scan2(int* __restrict__ partials, int nb) {
    __shared__ int wtot[2];
    int t = threadIdx.x;
    int carry = 0;
    for (int base = 0; base < nb; base += 128) {
        int idx = base + t;
        int p = (idx < nb) ? partials[idx] : 0;
        int v = p;
        #pragma unroll
        for (int d = 1; d < 64; d <<= 1) {
            int q = __shfl_up(v, d, 64);
            if ((t & 63) >= d) v += q;
        }
        if ((t & 63) == 63) wtot[t >> 6] = v;
        __syncthreads();
        int add = (t >> 6) ? wtot[0] : 0;
        int incl = v + add + carry;
        if (idx < nb) partials[idx] = incl - p;
        carry += wtot[0] + wtot[1];
        __syncthreads();
    }
}

__global__ void k_scan3(int* __restrict__ row_ptr, const int* __restrict__ partials, int n) {
    int i = blockIdx.x * 1024 + threadIdx.x;
    if (i < n) row_ptr[i + 1] += partials[i >> 10];
    if (i == 0) row_ptr[0] = 0;
}

// ---- binning pass: histogram -> parallel global claim -> direct ranked write ----
__global__ __launch_bounds__(256) void k_bin(const int* __restrict__ ei,
                                             const int* __restrict__ row_ptr,
                                             int* __restrict__ bfill,
                                             uint32_t* __restrict__ pair_buf,
                                             int E, int nbkt) {
    __shared__ int hist[256], gbase[256], hcur[256];
    const int tid = threadIdx.x;
    const int e0 = blockIdx.x * TILE_E;
    hist[tid] = 0;
    __syncthreads();

    int dreg[TILE_E / 256];
    #pragma unroll
    for (int k = 0; k < TILE_E / 256; ++k) {
        int e = e0 + k * 256 + tid;
        int d = (e < E) ? ei[E + e] : -1;
        dreg[k] = d;
        if (d >= 0) atomicAdd(&hist[d >> BKT_SHIFT], 1);
    }
    __syncthreads();

    if (tid < nbkt) {
        int h = hist[tid];
        int g = (h > 0) ? atomicAdd(&bfill[tid], h) : 0;
        gbase[tid] = row_ptr[tid << BKT_SHIFT] + g;
        hcur[tid] = 0;
    }
    __syncthreads();

    #pragma unroll
    for (int k = 0; k < TILE_E / 256; ++k) {
        int d = dreg[k];
        if (d >= 0) {
            int e = e0 + k * 256 + tid;
            int s = ei[e];
            int b = d >> BKT_SHIFT;
            int r = atomicAdd(&hcur[b], 1);
            pair_buf[(size_t)gbase[b] + r] =
                ((uint32_t)s << BKT_SHIFT) | (uint32_t)(d & (BKT_NODES - 1));
        }
    }
}

// ---- fill pass 2: NSLICE blocks per bucket, localized scatter, global fil ----
__global__ __launch_bounds__(256) void k_fill2(const uint32_t* __restrict__ pair_buf,
                                               const int* __restrict__ row_ptr,
                                               int* __restrict__ fil,
                                               int* __restrict__ col_idx, int n) {
    const int b = blockIdx.x / NSLICE;
    const int sl = blockIdx.x - b * NSLICE;
    const int n0 = b << BKT_SHIFT;
    const int n1 = min(n, n0 + BKT_NODES);
    const int s = row_ptr[n0], e = row_ptr[n1];
    for (int i = s + sl * 256 + threadIdx.x; i < e; i += 256 * NSLICE) {
        uint32_t pk = pair_buf[i];
        int dl = pk & (BKT_NODES - 1);
        int src = (int)(pk >> BKT_SHIFT);
        int node = n0 + dl;
        int slot = row_ptr[node] + atomicAdd(&fil[node], 1);
        col_idx[slot] = src;
    }
}

// ---- mean-aggregate: one wave per node, lane owns 2 features, edge loop x8 ----
__global__ void k_aggregate(const bf16* __restrict__ src, bf16* __restrict__ dst,
                            const int* __restrict__ row_ptr, const int* __restrict__ col_idx,
                            const float* __restrict__ inv_deg, int n) {
    int node = blockIdx.x * 4 + (threadIdx.x >> 6);
    int lane = threadIdx.x & 63;
    if (node >= n) return;
    int e0 = row_ptr[node], e1 = row_ptr[node + 1];
    const bf16* sp = src + (lane << 1);
    float f0 = 0.f, f1 = 0.f;
    int e = e0;
    for (; e + 7 < e1; e += 8) {
        uint32_t u0 = *(const uint32_t*)(sp + (size_t)col_idx[e] * 128);
        uint32_t u1 = *(const uint32_t*)(sp + (size_t)col_idx[e + 1] * 128);
        uint32_t u2 = *(const uint32_t*)(sp + (size_t)col_idx[e + 2] * 128);
        uint32_t u3 = *(const uint32_t*)(sp + (size_t)col_idx[e + 3] * 128);
        uint32_t u4 = *(const uint32_t*)(sp + (size_t)col_idx[e + 4] * 128);
        uint32_t u5 = *(const uint32_t*)(sp + (size_t)col_idx[e + 5] * 128);
        uint32_t u6 = *(const uint32_t*)(sp + (size_t)col_idx[e + 6] * 128);
        uint32_t u7 = *(const uint32_t*)(sp + (size_t)col_idx[e + 7] * 128);
        f0 += ((bf_lo(u0) + bf_lo(u1)) + (bf_lo(u2) + bf_lo(u3))) +
              ((bf_lo(u4) + bf_lo(u5)) + (bf_lo(u6) + bf_lo(u7)));
        f1 += ((bf_hi(u0) + bf_hi(u1)) + (bf_hi(u2) + bf_hi(u3))) +
              ((bf_hi(u4) + bf_hi(u5)) + (bf_hi(u6) + bf_hi(u7)));
    }
    for (; e < e1; ++e) {
        uint32_t u0 = *(const uint32_t*)(sp + (size_t)col_idx[e] * 128);
        f0 += bf_lo(u0);
        f1 += bf_hi(u0);
    }
    float inv = inv_deg[node];
    bf16x2 o; o[0] = (bf16)(f0 * inv); o[1] = (bf16)(f1 * inv);
    *(bf16x2*)(dst + (size_t)node * 128 + (lane << 1)) = o;
}

// ---- MFMA GEMM: out[M x ncols] = [A1|A2] @ Bt^T (+ bias), fused BN stats ----
// mode 0 (yl8==nullptr): fp32 out + bias; per-column sum/sumsq -> stats.
// mode 1: cols 0..46 -> yl8 (fp8 e4m3, row stride 64); 47..93 -> yrbf (bf16, stride 48).
__global__ __launch_bounds__(256) void k_gemm(
    const bf16* __restrict__ A1, const bf16* __restrict__ A2, const bf16* __restrict__ Bt,
    const float* __restrict__ bias, float* __restrict__ outF,
    fp8* __restrict__ yl8, bf16* __restrict__ yrbf, float* __restrict__ stats,
    int M, int ncols, int ldc, int cps, int chunks, int ldb) {
    __shared__ __attribute__((aligned(16))) bf16 sA[4096];
    __shared__ __attribute__((aligned(16))) bf16 sB[4096];
    __shared__ float scol[128], scol2[128];
    const int tid = threadIdx.x;
    const int w = tid >> 6, l = tid & 63;
    const int q = l >> 4, r = l & 15;
    const int r0 = blockIdx.x * 128;
    if (tid < 128) { scol[tid] = 0.f; scol2[tid] = 0.f; }
    f32x4 acc[2][8];
    #pragma unroll
    for (int i = 0; i < 2; ++i)
        #pragma unroll
        for (int j = 0; j < 8; ++j) { acc[i][j][0] = 0.f; acc[i][j][1] = 0.f; acc[i][j][2] = 0.f; acc[i][j][3] = 0.f; }

    for (int c = 0; c < chunks; ++c) {
        const bf16* As = (c < cps) ? A1 : A2;
        const int ka = (c < cps ? c : c - cps) * 32;
        __syncthreads();
        #pragma unroll
        for (int i = 0; i < 2; ++i) {
            const int T = w * 2 + i;
            const bf16* ga = As + (size_t)(r0 + T * 16 + r) * 128 + ka + q * 8;
            const bf16* gb = Bt + (T * 16 + r) * ldb + c * 32 + q * 8;
            uint32_t la = (uint32_t)(uintptr_t)(&sA[T * 512]);
            uint32_t lb = (uint32_t)(uintptr_t)(&sB[T * 512]);
            __builtin_amdgcn_global_load_lds((AS1 uint32_t*)(uintptr_t)ga, (AS3 uint32_t*)la, 16, 0, 0);
            __builtin_amdgcn_global_load_lds((AS1 uint32_t*)(uintptr_t)gb, (AS3 uint32_t*)lb, 16, 0, 0);
        }
        __syncthreads();
        bf16x8 af0 = *(const bf16x8*)&sA[(w * 2 + 0) * 512 + q * 128 + r * 8];
        bf16x8 af1 = *(const bf16x8*)&sA[(w * 2 + 1) * 512 + q * 128 + r * 8];
        #pragma unroll
        for (int ct = 0; ct < 8; ++ct) {
            bf16x8 bv = *(const bf16x8*)&sB[ct * 512 + q * 128 + r * 8];
            acc[0][ct] = __builtin_amdgcn_mfma_f32_16x16x32_bf16(af0, bv, acc[0][ct], 0, 0, 0);
            acc[1][ct] = __builtin_amdgcn_mfma_f32_16x16x32_bf16(af1, bv, acc[1][ct], 0, 0, 0);
        }
    }
    if (yl8 == nullptr) {
        #pragma unroll
        for (int ct = 0; ct < 8; ++ct) {
            int col = ct * 16 + r;
            float bv = bias ? bias[col] : 0.f;
            float s_c = 0.f, q_c = 0.f;
            #pragma unroll
            for (int rt = 0; rt < 2; ++rt) {
                #pragma unroll
                for (int j = 0; j < 4; ++j) {
                    int row = r0 + w * 32 + rt * 16 + q * 4 + j;
                    if (row < M) {
                        float v = acc[rt][ct][j] + bv;
                        outF[(size_t)row * ldc + col] = v;
                        s_c += v; q_c += v * v;
                    }
                }
            }
            atomicAdd(&scol[col], s_c);
            atomicAdd(&scol2[col], q_c);
        }
        __syncthreads();
        if (tid < 128) {
            atomicAdd(&stats[tid], scol[tid]);
            atomicAdd(&stats[128 + tid], scol2[tid]);
        }
    } else {
        #pragma unroll
        for (int rt = 0; rt < 2; ++rt) {
            #pragma unroll
            for (int ct = 0; ct < 8; ++ct) {
                int col = ct * 16 + r;
                #pragma unroll
                for (int j = 0; j < 4; ++j) {
                    int row = r0 + w * 32 + rt * 16 + q * 4 + j;
                    if (row >= M) continue;
                    if (col < 47)      yl8[(size_t)row * 64 + col] = fp8(acc[rt][ct][j]);
                    else if (col < 94) yrbf[(size_t)row * 48 + (col - 47)] = (bf16)acc[rt][ct][j];
                }
            }
        }
    }
}

// ---- BN apply + ReLU -> bf16 ----
__global__ void k_bn_apply(const float* __restrict__ h, const float* __restrict__ sums,
                           const float* __restrict__ gma, const float* __restrict__ bta,
                           bf16* __restrict__ out, int n) {
    int g = blockIdx.x * blockDim.x + threadIdx.x;
    int row = g >> 6, c2 = g & 63;
    if (row >= n) return;
    int col = c2 << 1;
    float invn = 1.0f / (float)n;
    float mu0 = sums[col] * invn, mu1 = sums[col + 1] * invn;
    float v0 = sums[128 + col] * invn - mu0 * mu0;
    float v1 = sums[128 + col + 1] * invn - mu1 * mu1;
    float sc0 = gma[col] * rsqrtf(v0 + BN_EPS);
    float sc1 = gma[col + 1] * rsqrtf(v1 + BN_EPS);
    float sh0 = bta[col] - mu0 * sc0;
    float sh1 = bta[col + 1] - mu1 * sc1;
    float2 hv = *(const float2*)(h + (size_t)row * 128 + col);
    float r0 = fmaxf(hv.x * sc0 + sh0, 0.f);
    float r1 = fmaxf(hv.y * sc1 + sh1, 0.f);
    bf16x2 o; o[0] = (bf16)r0; o[1] = (bf16)r1;
    *(bf16x2*)(out + (size_t)row * 128 + col) = o;
}

// ---- final: gather-mean of yl (fp8, stride 64 = 1 line/edge) + yr + bl2, log_softmax ----
__global__ void k_final(const fp8* __restrict__ yl, const bf16* __restrict__ yr,
                        const int* __restrict__ row_ptr, const int* __restrict__ col_idx,
                        const float* __restrict__ inv_deg, const float* __restrict__ bl2,
                        float* __restrict__ out, int n) {
    int node = blockIdx.x * 4 + (threadIdx.x >> 6);
    int c = threadIdx.x & 63;
    if (node >= n) return;
    int e0 = row_ptr[node], e1 = row_ptr[node + 1];
    bool valid = (c < 47);
    const fp8* ylc = yl + c;        // all 64 lanes read: one 64B line per edge
    float acc = 0.f;
    int e = e0;
    for (; e + 7 < e1; e += 8) {
        float v0 = (float)ylc[(size_t)col_idx[e] * 64];
        float v1 = (float)ylc[(size_t)col_idx[e + 1] * 64];
        float v2 = (float)ylc[(size_t)col_idx[e + 2] * 64];
        float v3 = (float)ylc[(size_t)col_idx[e + 3] * 64];
        float v4 = (float)ylc[(size_t)col_idx[e + 4] * 64];
        float v5 = (float)ylc[(size_t)col_idx[e + 5] * 64];
        float v6 = (float)ylc[(size_t)col_idx[e + 6] * 64];
        float v7 = (float)ylc[(size_t)col_idx[e + 7] * 64];
        acc += ((v0 + v1) + (v2 + v3)) + ((v4 + v5) + (v6 + v7));
    }
    for (; e < e1; ++e) acc += (float)ylc[(size_t)col_idx[e] * 64];
    int cc = valid ? c : 0;
    float yv = (float)yr[(size_t)node * 48 + cc];
    float bv = bl2[cc];
    float val = valid ? (acc * inv_deg[node] + yv + bv) : -__builtin_inff();
    float m = val;
    #pragma unroll
    for (int o = 32; o > 0; o >>= 1) m = fmaxf(m, __shfl_xor(m, o, 64));
    float ex = valid ? expf(val - m) : 0.f;
    float sum = ex;
    #pragma unroll
    for (int o = 32; o > 0; o >>= 1) sum += __shfl_xor(sum, o, 64);
    if (valid) out[(size_t)node * 47 + c] = val - m - logf(sum);
}

extern "C" void kernel_launch(void* const* d_in, const int* in_sizes, int n_in,
                              void* d_out, int out_size, void* d_ws, size_t ws_size,
                              hipStream_t stream) {
    const float* x   = (const float*)d_in[0];
    const int*   ei  = (const int*)d_in[1];
    const float* Wl0 = (const float*)d_in[2];
    const float* bl0 = (const float*)d_in[3];
    const float* Wr0 = (const float*)d_in[4];
    const float* g0  = (const float*)d_in[5];
    const float* be0 = (const float*)d_in[6];
    const float* Wl1 = (const float*)d_in[7];
    const float* bl1 = (const float*)d_in[8];
    const float* Wr1 = (const float*)d_in[9];
    const float* g1  = (const float*)d_in[10];
    const float* be1 = (const float*)d_in[11];
    const float* Wl2 = (const float*)d_in[12];
    const float* bl2 = (const float*)d_in[13];
    const float* Wr2 = (const float*)d_in[14];
    float* out = (float*)d_out;

    const int N  = in_sizes[0] / 128;
    const int E  = in_sizes[1] / 2;
    const int NP = ((N + 127) / 128) * 128;
    const int NBKT = (N + BKT_NODES - 1) / BKT_NODES;

    char* p = (char*)d_ws;
    size_t off = 0;
    auto alloc = [&](size_t b) { char* r = p + off; off += (b + 255) & ~(size_t)255; return r; };
    // zero-init region (one memset): deg, fil, bfill, bnsum
    int*   deg     = (int*)alloc((size_t)N * 4);
    int*   fil     = (int*)alloc((size_t)N * 4);
    int*   bfill   = (int*)alloc(1024 * 4);
    float* bnsum   = (float*)alloc(512 * 4);
    size_t zero_span = off;
    int*   row_ptr = (int*)alloc((size_t)(N + 1) * 4);
    float* invd    = (float*)alloc((size_t)N * 4);
    int*   col_idx = (int*)alloc((size_t)E * 4);
    uint32_t* pair_buf = (uint32_t*)alloc((size_t)E * 4);
    int*   partials= (int*)alloc(1024 * 4);
    bf16*  x_bf    = (bf16*)alloc((size_t)NP * 128 * 2);
    bf16*  aggbf   = (bf16*)alloc((size_t)NP * 128 * 2);
    bf16*  hbf     = (bf16*)alloc((size_t)NP * 128 * 2);
    float* bufF    = (float*)alloc((size_t)NP * 128 * 4 + 256);
    bf16*  Bt0     = (bf16*)alloc(128 * 256 * 2);
    bf16*  Bt1     = (bf16*)alloc(128 * 256 * 2);
    bf16*  Bt2     = (bf16*)alloc(128 * 128 * 2);
    // layer-2 outputs alias bufF (free by then): yl fp8 [NP][64], yr bf16 [NP][48]
    fp8*   yl8  = (fp8*)bufF;
    bf16*  yrbf = (bf16*)((char*)bufF + (size_t)NP * 64);

    hipMemsetAsync(deg, 0, zero_span, stream);

    int n4 = N * 128 / 4;
    int setupBlocks = (n4 + 255) / 256;
    k_setup<<<setupBlocks, 256, 0, stream>>>(x, x_bf, n4, ei, deg, E,
                                             Wl0, Wr0, Wl1, Wr1, Wl2, Wr2, Bt0, Bt1, Bt2);
    int nb = (N + 1023) / 1024;
    k_scan1<<<nb, 1024, 0, stream>>>(deg, row_ptr, invd, partials, N);
    k_scan2<<<1, 128, 0, stream>>>(partials, nb);
    k_scan3<<<nb, 1024, 0, stream>>>(row_ptr, partials, N);
    int binBlocks = (E + TILE_E - 1) / TILE_E;
    k_bin<<<binBlocks, 256, 0, stream>>>(ei, row_ptr, bfill, pair_buf, E, NBKT);
    k_fill2<<<NBKT * NSLICE, 256, 0, stream>>>(pair_buf, row_ptr, fil, col_idx, N);

    int aggBlocks  = (N + 3) / 4;
    int gemmBlocks = NP / 128;

    // Layer 0
    k_aggregate<<<aggBlocks, 256, 0, stream>>>(x_bf, aggbf, row_ptr, col_idx, invd, N);
    k_gemm<<<gemmBlocks, 256, 0, stream>>>(aggbf, x_bf, Bt0, bl0, bufF, nullptr, nullptr, bnsum, N, 128, 128, 4, 8, 256);
    k_bn_apply<<<(N * 64 + 255) / 256, 256, 0, stream>>>(bufF, bnsum, g0, be0, hbf, N);
    // Layer 1
    k_aggregate<<<aggBlocks, 256, 0, stream>>>(hbf, aggbf, row_ptr, col_idx, invd, N);
    k_gemm<<<gemmBlocks, 256, 0, stream>>>(aggbf, hbf, Bt1, bl1, bufF, nullptr, nullptr, bnsum + 256, N, 128, 128, 4, 8, 256);
    k_bn_apply<<<(N * 64 + 255) / 256, 256, 0, stream>>>(bufF, bnsum + 256, g1, be1, hbf, N);
    // Layer 2: project to yl (fp8, stride 64) / yr (bf16), then gather + log_softmax
    k_gemm<<<gemmBlocks, 256, 0, stream>>>(hbf, hbf, Bt2, nullptr, nullptr, yl8, yrbf, nullptr, N, 94, 96, 4, 4, 128);
    k_final<<<aggBlocks, 256, 0, stream>>>(yl8, yrbf, row_ptr, col_idx, invd, bl2, out, N);
}

// Round 7
// 578.397 us; speedup vs baseline: 1.4850x; 1.1482x over previous
//
#include <hip/hip_runtime.h>
#include <hip/hip_fp8.h>
#include <stdint.h>

#define AS1 __attribute__((address_space(1)))
#define AS3 __attribute__((address_space(3)))

typedef __bf16 bf16;
typedef __bf16 bf16x2 __attribute__((ext_vector_type(2)));
typedef __bf16 bf16x4v __attribute__((ext_vector_type(4)));
typedef __bf16 bf16x8 __attribute__((ext_vector_type(8)));
typedef float f32x4 __attribute__((ext_vector_type(4)));
typedef __hip_fp8_e4m3 fp8;

#define BN_EPS 1e-5f
#define BKT_SHIFT 8              // 256 nodes per bucket
#define BKT_NODES 256
#define TILE_E 2048              // edges per binning block

__device__ __forceinline__ float fp8_to_f32(unsigned char b) {
    fp8 v; v.__x = (__hip_fp8_storage_t)b; return (float)v;
}

// ---- fused setup: weight transpose+cvt, x fp32 -> bf16 + fp8 ----
__global__ void k_setup(const float* __restrict__ x, bf16* __restrict__ x_bf,
                        unsigned char* __restrict__ x8, int n4,
                        const float* __restrict__ Wl0, const float* __restrict__ Wr0,
                        const float* __restrict__ Wl1, const float* __restrict__ Wr1,
                        const float* __restrict__ Wl2, const float* __restrict__ Wr2,
                        bf16* __restrict__ Bt0, bf16* __restrict__ Bt1, bf16* __restrict__ Bt2) {
    int g = blockIdx.x * 256 + threadIdx.x;
    if (g < n4) {
        float4 v = ((const float4*)x)[g];
        bf16x4v o; o[0] = (bf16)v.x; o[1] = (bf16)v.y; o[2] = (bf16)v.z; o[3] = (bf16)v.w;
        ((bf16x4v*)x_bf)[g] = o;
        uchar4 o8;
        o8.x = fp8(v.x).__x; o8.y = fp8(v.y).__x; o8.z = fp8(v.z).__x; o8.w = fp8(v.w).__x;
        ((uchar4*)x8)[g] = o8;
    }
    if (blockIdx.x < 128) {
        int idx = g;                 // 32768 threads: c in [0,128), k in [0,256)
        int c = idx >> 8, k = idx & 255;
        float v0 = (k < 128) ? Wl0[k * 128 + c] : Wr0[(k - 128) * 128 + c];
        Bt0[c * 256 + k] = (bf16)v0;
        float v1 = (k < 128) ? Wl1[k * 128 + c] : Wr1[(k - 128) * 128 + c];
        Bt1[c * 256 + k] = (bf16)v1;
        if (k < 128) {
            float v2 = 0.f;
            if (c < 47)      v2 = Wl2[k * 47 + c];
            else if (c < 94) v2 = Wr2[k * 47 + (c - 47)];
            Bt2[c * 128 + k] = (bf16)v2;
        }
    }
}

// ---- bucket totals: LDS histogram of dst>>8, few global atomics ----
__global__ __launch_bounds__(256) void k_bcount(const int* __restrict__ ei,
                                                int* __restrict__ btot, int E, int nbkt) {
    __shared__ int hist[512];
    const int tid = threadIdx.x;
    hist[tid] = 0; hist[tid + 256] = 0;
    __syncthreads();
    const int e0 = blockIdx.x * 4096;
    #pragma unroll
    for (int k = 0; k < 4; ++k) {
        int i4 = (e0 >> 2) + k * 256 + tid;
        if (i4 * 4 + 3 < E) {
            int4 d4 = ((const int4*)(ei + E))[i4];
            atomicAdd(&hist[d4.x >> BKT_SHIFT], 1);
            atomicAdd(&hist[d4.y >> BKT_SHIFT], 1);
            atomicAdd(&hist[d4.z >> BKT_SHIFT], 1);
            atomicAdd(&hist[d4.w >> BKT_SHIFT], 1);
        } else {
            for (int e = i4 * 4; e < min(E, i4 * 4 + 4); ++e)
                atomicAdd(&hist[ei[E + e] >> BKT_SHIFT], 1);
        }
    }
    __syncthreads();
    for (int b = tid; b < nbkt; b += 256)
        if (hist[b]) atomicAdd(&btot[b], hist[b]);
}

// ---- scan bucket totals -> bbase[0..nbkt] (exclusive), row_ptr[N]=E ----
__global__ void k_bscan(const int* __restrict__ btot, int* __restrict__ bbase,
                        int* __restrict__ row_ptr, int n, int E, int nbkt) {
    __shared__ int wsum[8];
    int tid = threadIdx.x, lane = tid & 63, wid = tid >> 6;
    int v = (tid < nbkt) ? btot[tid] : 0;
    int incl = v;
    #pragma unroll
    for (int d = 1; d < 64; d <<= 1) {
        int t = __shfl_up(incl, d, 64);
        if (lane >= d) incl += t;
    }
    if (lane == 63) wsum[wid] = incl;
    __syncthreads();
    if (tid == 0) {
        int c = 0;
        #pragma unroll
        for (int i = 0; i < 8; ++i) { int t = wsum[i]; wsum[i] = c; c += t; }
    }
    __syncthreads();
    int tot = incl + wsum[wid];
    if (tid < nbkt) bbase[tid + 1] = tot;
    if (tid == 0) { bbase[0] = 0; row_ptr[n] = E; }
}

// ---- binning pass: histogram -> parallel global claim -> direct ranked write ----
// pair = (src << 8) | (dst & 255); bucket = dst >> 8.
__global__ __launch_bounds__(256) void k_bin(const int* __restrict__ ei,
                                             const int* __restrict__ bbase,
                                             int* __restrict__ bfill,
                                             uint32_t* __restrict__ pair_buf,
                                             int E, int nbkt) {
    __shared__ int hist[512], gbase[512], hcur[512];
    const int tid = threadIdx.x;
    const int e0 = blockIdx.x * TILE_E;
    hist[tid] = 0; hist[tid + 256] = 0;
    __syncthreads();

    int dreg[TILE_E / 256];
    #pragma unroll
    for (int k = 0; k < TILE_E / 256; ++k) {
        int e = e0 + k * 256 + tid;
        int d = (e < E) ? ei[E + e] : -1;
        dreg[k] = d;
        if (d >= 0) atomicAdd(&hist[d >> BKT_SHIFT], 1);
    }
    __syncthreads();

    for (int b = tid; b < nbkt; b += 256) {
        int h = hist[b];
        int g = (h > 0) ? atomicAdd(&bfill[b], h) : 0;
        gbase[b] = bbase[b] + g;
        hcur[b] = 0;
    }
    __syncthreads();

    #pragma unroll
    for (int k = 0; k < TILE_E / 256; ++k) {
        int d = dreg[k];
        if (d >= 0) {
            int e = e0 + k * 256 + tid;
            int s = ei[e];
            int b = d >> BKT_SHIFT;
            int r = atomicAdd(&hcur[b], 1);
            pair_buf[(size_t)gbase[b] + r] =
                ((uint32_t)s << BKT_SHIFT) | (uint32_t)(d & (BKT_NODES - 1));
        }
    }
}

// ---- fill: one block per bucket. Local deg hist -> scan -> row_ptr/inv_deg,
//      then rank-scatter col_idx. All per-node state in LDS. ----
__global__ __launch_bounds__(256) void k_fill2(const uint32_t* __restrict__ pair_buf,
                                               const int* __restrict__ bbase,
                                               int* __restrict__ row_ptr,
                                               float* __restrict__ inv_deg,
                                               int* __restrict__ col_idx, int n) {
    __shared__ int hist[256], excl[256], hcur[256], wsum4[4];
    const int b = blockIdx.x;
    const int tid = threadIdx.x, lane = tid & 63, wid = tid >> 6;
    const int n0 = b << BKT_SHIFT;
    const int s = bbase[b], e = bbase[b + 1];
    hist[tid] = 0; hcur[tid] = 0;
    __syncthreads();
    for (int i = s + tid; i < e; i += 256)
        atomicAdd(&hist[pair_buf[i] & (BKT_NODES - 1)], 1);
    __syncthreads();
    int v = hist[tid];
    int incl = v;
    #pragma unroll
    for (int d = 1; d < 64; d <<= 1) {
        int t = __shfl_up(incl, d, 64);
        if (lane >= d) incl += t;
    }
    if (lane == 63) wsum4[wid] = incl;
    __syncthreads();
    if (tid == 0) {
        int c = 0;
        #pragma unroll
        for (int i = 0; i < 4; ++i) { int t = wsum4[i]; wsum4[i] = c; c += t; }
    }
    __syncthreads();
    int ex = incl - v + wsum4[wid];
    excl[tid] = ex;
    int node = n0 + tid;
    if (node < n) {
        row_ptr[node] = s + ex;
        inv_deg[node] = 1.0f / (float)(v > 1 ? v : 1);
    }
    __syncthreads();
    for (int i = s + tid; i < e; i += 256) {
        uint32_t pk = pair_buf[i];
        int dl = pk & (BKT_NODES - 1);
        int r = atomicAdd(&hcur[dl], 1);
        col_idx[s + excl[dl] + r] = (int)(pk >> BKT_SHIFT);
    }
}

// ---- mean-aggregate from fp8 table (128 B/row): wave per node, lane = 2 feats ----
__global__ void k_aggregate(const unsigned char* __restrict__ src8, bf16* __restrict__ dst,
                            const int* __restrict__ row_ptr, const int* __restrict__ col_idx,
                            const float* __restrict__ inv_deg, int n) {
    int node = blockIdx.x * 4 + (threadIdx.x >> 6);
    int lane = threadIdx.x & 63;
    if (node >= n) return;
    int e0 = row_ptr[node], e1 = row_ptr[node + 1];
    const unsigned char* sp = src8 + (lane << 1);
    float f0 = 0.f, f1 = 0.f;
    int e = e0;
    for (; e + 7 < e1; e += 8) {
        uint16_t u0 = *(const uint16_t*)(sp + (size_t)col_idx[e] * 128);
        uint16_t u1 = *(const uint16_t*)(sp + (size_t)col_idx[e + 1] * 128);
        uint16_t u2 = *(const uint16_t*)(sp + (size_t)col_idx[e + 2] * 128);
        uint16_t u3 = *(const uint16_t*)(sp + (size_t)col_idx[e + 3] * 128);
        uint16_t u4 = *(const uint16_t*)(sp + (size_t)col_idx[e + 4] * 128);
        uint16_t u5 = *(const uint16_t*)(sp + (size_t)col_idx[e + 5] * 128);
        uint16_t u6 = *(const uint16_t*)(sp + (size_t)col_idx[e + 6] * 128);
        uint16_t u7 = *(const uint16_t*)(sp + (size_t)col_idx[e + 7] * 128);
        f0 += ((fp8_to_f32(u0 & 255) + fp8_to_f32(u1 & 255)) + (fp8_to_f32(u2 & 255) + fp8_to_f32(u3 & 255))) +
              ((fp8_to_f32(u4 & 255) + fp8_to_f32(u5 & 255)) + (fp8_to_f32(u6 & 255) + fp8_to_f32(u7 & 255)));
        f1 += ((fp8_to_f32(u0 >> 8) + fp8_to_f32(u1 >> 8)) + (fp8_to_f32(u2 >> 8) + fp8_to_f32(u3 >> 8))) +
              ((fp8_to_f32(u4 >> 8) + fp8_to_f32(u5 >> 8)) + (fp8_to_f32(u6 >> 8) + fp8_to_f32(u7 >> 8)));
    }
    for (; e < e1; ++e) {
        uint16_t u0 = *(const uint16_t*)(sp + (size_t)col_idx[e] * 128);
        f0 += fp8_to_f32(u0 & 255);
        f1 += fp8_to_f32(u0 >> 8);
    }
    float inv = inv_deg[node];
    bf16x2 o; o[0] = (bf16)(f0 * inv); o[1] = (bf16)(f1 * inv);
    *(bf16x2*)(dst + (size_t)node * 128 + (lane << 1)) = o;
}

// ---- MFMA GEMM: out[M x ncols] = [A1|A2] @ Bt^T (+ bias), fused BN stats ----
__global__ __launch_bounds__(256) void k_gemm(
    const bf16* __restrict__ A1, const bf16* __restrict__ A2, const bf16* __restrict__ Bt,
    const float* __restrict__ bias, float* __restrict__ outF,
    fp8* __restrict__ yl8, bf16* __restrict__ yrbf, float* __restrict__ stats,
    int M, int ncols, int ldc, int cps, int chunks, int ldb) {
    __shared__ __attribute__((aligned(16))) bf16 sA[4096];
    __shared__ __attribute__((aligned(16))) bf16 sB[4096];
    __shared__ float scol[128], scol2[128];
    const int tid = threadIdx.x;
    const int w = tid >> 6, l = tid & 63;
    const int q = l >> 4, r = l & 15;
    const int r0 = blockIdx.x * 128;
    if (tid < 128) { scol[tid] = 0.f; scol2[tid] = 0.f; }
    f32x4 acc[2][8];
    #pragma unroll
    for (int i = 0; i < 2; ++i)
        #pragma unroll
        for (int j = 0; j < 8; ++j) { acc[i][j][0] = 0.f; acc[i][j][1] = 0.f; acc[i][j][2] = 0.f; acc[i][j][3] = 0.f; }

    for (int c = 0; c < chunks; ++c) {
        const bf16* As = (c < cps) ? A1 : A2;
        const int ka = (c < cps ? c : c - cps) * 32;
        __syncthreads();
        #pragma unroll
        for (int i = 0; i < 2; ++i) {
            const int T = w * 2 + i;
            const bf16* ga = As + (size_t)(r0 + T * 16 + r) * 128 + ka + q * 8;
            const bf16* gb = Bt + (T * 16 + r) * ldb + c * 32 + q * 8;
            uint32_t la = (uint32_t)(uintptr_t)(&sA[T * 512]);
            uint32_t lb = (uint32_t)(uintptr_t)(&sB[T * 512]);
            __builtin_amdgcn_global_load_lds((AS1 uint32_t*)(uintptr_t)ga, (AS3 uint32_t*)la, 16, 0, 0);
            __builtin_amdgcn_global_load_lds((AS1 uint32_t*)(uintptr_t)gb, (AS3 uint32_t*)lb, 16, 0, 0);
        }
        __syncthreads();
        bf16x8 af0 = *(const bf16x8*)&sA[(w * 2 + 0) * 512 + q * 128 + r * 8];
        bf16x8 af1 = *(const bf16x8*)&sA[(w * 2 + 1) * 512 + q * 128 + r * 8];
        #pragma unroll
        for (int ct = 0; ct < 8; ++ct) {
            bf16x8 bv = *(const bf16x8*)&sB[ct * 512 + q * 128 + r * 8];
            acc[0][ct] = __builtin_amdgcn_mfma_f32_16x16x32_bf16(af0, bv, acc[0][ct], 0, 0, 0);
            acc[1][ct] = __builtin_amdgcn_mfma_f32_16x16x32_bf16(af1, bv, acc[1][ct], 0, 0, 0);
        }
    }
    if (yl8 == nullptr) {
        #pragma unroll
        for (int ct = 0; ct < 8; ++ct) {
            int col = ct * 16 + r;
            float bv = bias ? bias[col] : 0.f;
            float s_c = 0.f, q_c = 0.f;
            #pragma unroll
            for (int rt = 0; rt < 2; ++rt) {
                #pragma unroll
                for (int j = 0; j < 4; ++j) {
                    int row = r0 + w * 32 + rt * 16 + q * 4 + j;
                    if (row < M) {
                        float v = acc[rt][ct][j] + bv;
                        outF[(size_t)row * ldc + col] = v;
                        s_c += v; q_c += v * v;
                    }
                }
            }
            atomicAdd(&scol[col], s_c);
            atomicAdd(&scol2[col], q_c);
        }
        __syncthreads();
        if (tid < 128) {
            atomicAdd(&stats[tid], scol[tid]);
            atomicAdd(&stats[128 + tid], scol2[tid]);
        }
    } else {
        #pragma unroll
        for (int rt = 0; rt < 2; ++rt) {
            #pragma unroll
            for (int ct = 0; ct < 8; ++ct) {
                int col = ct * 16 + r;
                #pragma unroll
                for (int j = 0; j < 4; ++j) {
                    int row = r0 + w * 32 + rt * 16 + q * 4 + j;
                    if (row >= M) continue;
                    if (col < 47)      yl8[(size_t)row * 64 + col] = fp8(acc[rt][ct][j]);
                    else if (col < 94) yrbf[(size_t)row * 48 + (col - 47)] = (bf16)acc[rt][ct][j];
                }
            }
        }
    }
}

// ---- BN apply + ReLU -> bf16 (GEMM input) + fp8 (gather table) ----
__global__ void k_bn_apply(const float* __restrict__ h, const float* __restrict__ sums,
                           const float* __restrict__ gma, const float* __restrict__ bta,
                           bf16* __restrict__ out, unsigned char* __restrict__ out8, int n) {
    int g = blockIdx.x * blockDim.x + threadIdx.x;
    int row = g >> 6, c2 = g & 63;
    if (row >= n) return;
    int col = c2 << 1;
    float invn = 1.0f / (float)n;
    float mu0 = sums[col] * invn, mu1 = sums[col + 1] * invn;
    float v0 = sums[128 + col] * invn - mu0 * mu0;
    float v1 = sums[128 + col + 1] * invn - mu1 * mu1;
    float sc0 = gma[col] * rsqrtf(v0 + BN_EPS);
    float sc1 = gma[col + 1] * rsqrtf(v1 + BN_EPS);
    float sh0 = bta[col] - mu0 * sc0;
    float sh1 = bta[col + 1] - mu1 * sc1;
    float2 hv = *(const float2*)(h + (size_t)row * 128 + col);
    float r0 = fmaxf(hv.x * sc0 + sh0, 0.f);
    float r1 = fmaxf(hv.y * sc1 + sh1, 0.f);
    bf16x2 o; o[0] = (bf16)r0; o[1] = (bf16)r1;
    *(bf16x2*)(out + (size_t)row * 128 + col) = o;
    uchar2 o8; o8.x = fp8(r0).__x; o8.y = fp8(r1).__x;
    *(uchar2*)(out8 + (size_t)row * 128 + col) = o8;
}

// ---- final: gather-mean of yl (fp8, stride 64 = 1 line/edge) + yr + bl2, log_softmax ----
__global__ void k_final(const fp8* __restrict__ yl, const bf16* __restrict__ yr,
                        const int* __restrict__ row_ptr, const int* __restrict__ col_idx,
                        const float* __restrict__ inv_deg, const float* __restrict__ bl2,
                        float* __restrict__ out, int n) {
    int node = blockIdx.x * 4 + (threadIdx.x >> 6);
    int c = threadIdx.x & 63;
    if (node >= n) return;
    int e0 = row_ptr[node], e1 = row_ptr[node + 1];
    bool valid = (c < 47);
    const fp8* ylc = yl + c;        // one 64B line per edge
    float acc = 0.f;
    int e = e0;
    for (; e + 7 < e1; e += 8) {
        float v0 = (float)ylc[(size_t)col_idx[e] * 64];
        float v1 = (float)ylc[(size_t)col_idx[e + 1] * 64];
        float v2 = (float)ylc[(size_t)col_idx[e + 2] * 64];
        float v3 = (float)ylc[(size_t)col_idx[e + 3] * 64];
        float v4 = (float)ylc[(size_t)col_idx[e + 4] * 64];
        float v5 = (float)ylc[(size_t)col_idx[e + 5] * 64];
        float v6 = (float)ylc[(size_t)col_idx[e + 6] * 64];
        float v7 = (float)ylc[(size_t)col_idx[e + 7] * 64];
        acc += ((v0 + v1) + (v2 + v3)) + ((v4 + v5) + (v6 + v7));
    }
    for (; e < e1; ++e) acc += (float)ylc[(size_t)col_idx[e] * 64];
    int cc = valid ? c : 0;
    float yv = (float)yr[(size_t)node * 48 + cc];
    float bv = bl2[cc];
    float val = valid ? (acc * inv_deg[node] + yv + bv) : -__builtin_inff();
    float m = val;
    #pragma unroll
    for (int o = 32; o > 0; o >>= 1) m = fmaxf(m, __shfl_xor(m, o, 64));
    float ex = valid ? expf(val - m) : 0.f;
    float sum = ex;
    #pragma unroll
    for (int o = 32; o > 0; o >>= 1) sum += __shfl_xor(sum, o, 64);
    if (valid) out[(size_t)node * 47 + c] = val - m - logf(sum);
}

extern "C" void kernel_launch(void* const* d_in, const int* in_sizes, int n_in,
                              void* d_out, int out_size, void* d_ws, size_t ws_size,
                              hipStream_t stream) {
    const float* x   = (const float*)d_in[0];
    const int*   ei  = (const int*)d_in[1];
    const float* Wl0 = (const float*)d_in[2];
    const float* bl0 = (const float*)d_in[3];
    const float* Wr0 = (const float*)d_in[4];
    const float* g0  = (const float*)d_in[5];
    const float* be0 = (const float*)d_in[6];
    const float* Wl1 = (const float*)d_in[7];
    const float* bl1 = (const float*)d_in[8];
    const float* Wr1 = (const float*)d_in[9];
    const float* g1  = (const float*)d_in[10];
    const float* be1 = (const float*)d_in[11];
    const float* Wl2 = (const float*)d_in[12];
    const float* bl2 = (const float*)d_in[13];
    const float* Wr2 = (const float*)d_in[14];
    float* out = (float*)d_out;

    const int N  = in_sizes[0] / 128;
    const int E  = in_sizes[1] / 2;
    const int NP = ((N + 127) / 128) * 128;
    const int NBKT = (N + BKT_NODES - 1) / BKT_NODES;

    char* p = (char*)d_ws;
    size_t off = 0;
    auto alloc = [&](size_t b) { char* r = p + off; off += (b + 255) & ~(size_t)255; return r; };
    // zero-init region (one memset): bfill, bnsum, btot
    int*   bfill   = (int*)alloc(1024 * 4);
    float* bnsum   = (float*)alloc(512 * 4);
    int*   btot    = (int*)alloc(512 * 4);
    size_t zero_span = off;
    int*   row_ptr = (int*)alloc((size_t)(N + 1) * 4);
    float* invd    = (float*)alloc((size_t)N * 4);
    int*   col_idx = (int*)alloc((size_t)E * 4);
    uint32_t* pair_buf = (uint32_t*)alloc((size_t)E * 4);
    int*   bbase   = (int*)alloc(1024 * 4);
    bf16*  x_bf    = (bf16*)alloc((size_t)NP * 128 * 2);
    bf16*  aggbf   = (bf16*)alloc((size_t)NP * 128 * 2);
    bf16*  hbf     = (bf16*)alloc((size_t)NP * 128 * 2);
    unsigned char* h8 = (unsigned char*)alloc((size_t)NP * 128);
    float* bufF    = (float*)alloc((size_t)NP * 128 * 4 + 256);
    bf16*  Bt0     = (bf16*)alloc(128 * 256 * 2);
    bf16*  Bt1     = (bf16*)alloc(128 * 256 * 2);
    bf16*  Bt2     = (bf16*)alloc(128 * 128 * 2);
    // aliases into bufF (sequentially dead/live): x8 (pre-GEMM0), yl8/yrbf (post-BN1)
    unsigned char* x8 = (unsigned char*)bufF;
    fp8*   yl8  = (fp8*)bufF;
    bf16*  yrbf = (bf16*)((char*)bufF + (size_t)NP * 64);

    hipMemsetAsync(bfill, 0, zero_span, stream);

    int n4 = N * 128 / 4;
    k_setup<<<(n4 + 255) / 256, 256, 0, stream>>>(x, x_bf, x8, n4,
                                                  Wl0, Wr0, Wl1, Wr1, Wl2, Wr2, Bt0, Bt1, Bt2);
    k_bcount<<<(E + 4095) / 4096, 256, 0, stream>>>(ei, btot, E, NBKT);
    k_bscan<<<1, 512, 0, stream>>>(btot, bbase, row_ptr, N, E, NBKT);
    k_bin<<<(E + TILE_E - 1) / TILE_E, 256, 0, stream>>>(ei, bbase, bfill, pair_buf, E, NBKT);
    k_fill2<<<NBKT, 256, 0, stream>>>(pair_buf, bbase, row_ptr, invd, col_idx, N);

    int aggBlocks  = (N + 3) / 4;
    int gemmBlocks = NP / 128;

    // Layer 0
    k_aggregate<<<aggBlocks, 256, 0, stream>>>(x8, aggbf, row_ptr, col_idx, invd, N);
    k_gemm<<<gemmBlocks, 256, 0, stream>>>(aggbf, x_bf, Bt0, bl0, bufF, nullptr, nullptr, bnsum, N, 128, 128, 4, 8, 256);
    k_bn_apply<<<(N * 64 + 255) / 256, 256, 0, stream>>>(bufF, bnsum, g0, be0, hbf, h8, N);
    // Layer 1
    k_aggregate<<<aggBlocks, 256, 0, stream>>>(h8, aggbf, row_ptr, col_idx, invd, N);
    k_gemm<<<gemmBlocks, 256, 0, stream>>>(aggbf, hbf, Bt1, bl1, bufF, nullptr, nullptr, bnsum + 256, N, 128, 128, 4, 8, 256);
    k_bn_apply<<<(N * 64 + 255) / 256, 256, 0, stream>>>(bufF, bnsum + 256, g1, be1, hbf, h8, N);
    // Layer 2: project to yl (fp8, stride 64) / yr (bf16), then gather + log_softmax
    k_gemm<<<gemmBlocks, 256, 0, stream>>>(hbf, hbf, Bt2, nullptr, nullptr, yl8, yrbf, nullptr, N, 94, 96, 4, 4, 128);
    k_final<<<aggBlocks, 256, 0, stream>>>(yl8, yrbf, row_ptr, col_idx, invd, bl2, out, N);
}

// Round 8
// 569.358 us; speedup vs baseline: 1.5085x; 1.0159x over previous
//
#include <hip/hip_runtime.h>
#include <hip/hip_fp8.h>
#include <stdint.h>

#define AS1 __attribute__((address_space(1)))
#define AS3 __attribute__((address_space(3)))

typedef __bf16 bf16;
typedef __bf16 bf16x2 __attribute__((ext_vector_type(2)));
typedef __bf16 bf16x4v __attribute__((ext_vector_type(4)));
typedef __bf16 bf16x8 __attribute__((ext_vector_type(8)));
typedef float f32x4 __attribute__((ext_vector_type(4)));
typedef float f32x2 __attribute__((ext_vector_type(2)));
typedef __hip_fp8_e4m3 fp8;

#define BN_EPS 1e-5f
#define BKT_SHIFT 8              // 256 nodes per bucket
#define BKT_NODES 256
#define TILE_E 2048              // edges per binning block

// ---- fused setup: weight cvt+transpose, x fp32 -> bf16 + fp8, bucket count ----
__global__ void k_setup(const float* __restrict__ x, bf16* __restrict__ x_bf,
                        unsigned char* __restrict__ x8, int n4,
                        const int* __restrict__ ei, int* __restrict__ btot, int E, int nbkt,
                        const float* __restrict__ Wl0, const float* __restrict__ Wr0,
                        const float* __restrict__ Wl1, const float* __restrict__ Wr1,
                        const float* __restrict__ Wl2, const float* __restrict__ Wr2,
                        bf16* __restrict__ Bt0, bf16* __restrict__ Bt1, bf16* __restrict__ Bt2) {
    __shared__ int hist[512];
    const int tid = threadIdx.x;
    int g = blockIdx.x * 256 + tid;
    if (g < n4) {
        float4 v = ((const float4*)x)[g];
        bf16x4v o; o[0] = (bf16)v.x; o[1] = (bf16)v.y; o[2] = (bf16)v.z; o[3] = (bf16)v.w;
        ((bf16x4v*)x_bf)[g] = o;
        uchar4 o8;
        o8.x = fp8(v.x).__x; o8.y = fp8(v.y).__x; o8.z = fp8(v.z).__x; o8.w = fp8(v.w).__x;
        ((uchar4*)x8)[g] = o8;
    }
    if (blockIdx.x < 128) {
        int idx = g;                 // 32768 threads: c in [0,128), k in [0,256)
        int c = idx >> 8, k = idx & 255;
        float v0 = (k < 128) ? Wl0[k * 128 + c] : Wr0[(k - 128) * 128 + c];
        Bt0[c * 256 + k] = (bf16)v0;
        float v1 = (k < 128) ? Wl1[k * 128 + c] : Wr1[(k - 128) * 128 + c];
        Bt1[c * 256 + k] = (bf16)v1;
        if (k < 128) {
            float v2 = 0.f;
            if (c < 47)      v2 = Wl2[k * 47 + c];
            else if (c < 94) v2 = Wr2[k * 47 + (c - 47)];
            Bt2[c * 128 + k] = (bf16)v2;
        }
    }
    // bucket histogram for blocks [0, ceil(E/4096))
    int nbinb = (E + 4095) / 4096;
    if (blockIdx.x < nbinb) {
        hist[tid] = 0; hist[tid + 256] = 0;
        __syncthreads();
        const int e0 = blockIdx.x * 4096;
        #pragma unroll
        for (int k = 0; k < 4; ++k) {
            int i4 = (e0 >> 2) + k * 256 + tid;
            if (i4 * 4 + 3 < E) {
                int4 d4 = ((const int4*)(ei + E))[i4];
                atomicAdd(&hist[d4.x >> BKT_SHIFT], 1);
                atomicAdd(&hist[d4.y >> BKT_SHIFT], 1);
                atomicAdd(&hist[d4.z >> BKT_SHIFT], 1);
                atomicAdd(&hist[d4.w >> BKT_SHIFT], 1);
            } else {
                for (int e = i4 * 4; e < min(E, i4 * 4 + 4); ++e)
                    atomicAdd(&hist[ei[E + e] >> BKT_SHIFT], 1);
            }
        }
        __syncthreads();
        for (int b = tid; b < nbkt; b += 256)
            if (hist[b]) atomicAdd(&btot[b], hist[b]);
    }
}

// ---- scan bucket totals -> bbase[0..nbkt] (exclusive), row_ptr[N]=E ----
__global__ void k_bscan(const int* __restrict__ btot, int* __restrict__ bbase,
                        int* __restrict__ row_ptr, int n, int E, int nbkt) {
    __shared__ int wsum[8];
    int tid = threadIdx.x, lane = tid & 63, wid = tid >> 6;
    int v = (tid < nbkt) ? btot[tid] : 0;
    int incl = v;
    #pragma unroll
    for (int d = 1; d < 64; d <<= 1) {
        int t = __shfl_up(incl, d, 64);
        if (lane >= d) incl += t;
    }
    if (lane == 63) wsum[wid] = incl;
    __syncthreads();
    if (tid == 0) {
        int c = 0;
        #pragma unroll
        for (int i = 0; i < 8; ++i) { int t = wsum[i]; wsum[i] = c; c += t; }
    }
    __syncthreads();
    int tot = incl + wsum[wid];
    if (tid < nbkt) bbase[tid + 1] = tot;
    if (tid == 0) { bbase[0] = 0; row_ptr[n] = E; }
}

// ---- binning pass: histogram -> parallel global claim -> direct ranked write ----
// pair = (src << 8) | (dst & 255); bucket = dst >> 8.
__global__ __launch_bounds__(256) void k_bin(const int* __restrict__ ei,
                                             const int* __restrict__ bbase,
                                             int* __restrict__ bfill,
                                             uint32_t* __restrict__ pair_buf,
                                             int E, int nbkt) {
    __shared__ int hist[512], gbase[512], hcur[512];
    const int tid = threadIdx.x;
    const int e0 = blockIdx.x * TILE_E;
    hist[tid] = 0; hist[tid + 256] = 0;
    __syncthreads();

    int dreg[TILE_E / 256];
    #pragma unroll
    for (int k = 0; k < TILE_E / 256; ++k) {
        int e = e0 + k * 256 + tid;
        int d = (e < E) ? ei[E + e] : -1;
        dreg[k] = d;
        if (d >= 0) atomicAdd(&hist[d >> BKT_SHIFT], 1);
    }
    __syncthreads();

    for (int b = tid; b < nbkt; b += 256) {
        int h = hist[b];
        int g = (h > 0) ? atomicAdd(&bfill[b], h) : 0;
        gbase[b] = bbase[b] + g;
        hcur[b] = 0;
    }
    __syncthreads();

    #pragma unroll
    for (int k = 0; k < TILE_E / 256; ++k) {
        int d = dreg[k];
        if (d >= 0) {
            int e = e0 + k * 256 + tid;
            int s = ei[e];
            int b = d >> BKT_SHIFT;
            int r = atomicAdd(&hcur[b], 1);
            pair_buf[(size_t)gbase[b] + r] =
                ((uint32_t)s << BKT_SHIFT) | (uint32_t)(d & (BKT_NODES - 1));
        }
    }
}

// ---- fill: one block per bucket. Local deg hist -> scan -> row_ptr/inv_deg,
//      then rank-scatter col_idx. ----
__global__ __launch_bounds__(256) void k_fill2(const uint32_t* __restrict__ pair_buf,
                                               const int* __restrict__ bbase,
                                               int* __restrict__ row_ptr,
                                               float* __restrict__ inv_deg,
                                               int* __restrict__ col_idx, int n) {
    __shared__ int hist[256], excl[256], hcur[256], wsum4[4];
    const int b = blockIdx.x;
    const int tid = threadIdx.x, lane = tid & 63, wid = tid >> 6;
    const int n0 = b << BKT_SHIFT;
    const int s = bbase[b], e = bbase[b + 1];
    hist[tid] = 0; hcur[tid] = 0;
    __syncthreads();
    for (int i = s + tid; i < e; i += 256)
        atomicAdd(&hist[pair_buf[i] & (BKT_NODES - 1)], 1);
    __syncthreads();
    int v = hist[tid];
    int incl = v;
    #pragma unroll
    for (int d = 1; d < 64; d <<= 1) {
        int t = __shfl_up(incl, d, 64);
        if (lane >= d) incl += t;
    }
    if (lane == 63) wsum4[wid] = incl;
    __syncthreads();
    if (tid == 0) {
        int c = 0;
        #pragma unroll
        for (int i = 0; i < 4; ++i) { int t = wsum4[i]; wsum4[i] = c; c += t; }
    }
    __syncthreads();
    int ex = incl - v + wsum4[wid];
    excl[tid] = ex;
    int node = n0 + tid;
    if (node < n) {
        row_ptr[node] = s + ex;
        inv_deg[node] = 1.0f / (float)(v > 1 ? v : 1);
    }
    __syncthreads();
    for (int i = s + tid; i < e; i += 256) {
        uint32_t pk = pair_buf[i];
        int dl = pk & (BKT_NODES - 1);
        int r = atomicAdd(&hcur[dl], 1);
        col_idx[s + excl[dl] + r] = (int)(pk >> BKT_SHIFT);
    }
}

// ---- mean-aggregate from fp8 table (128 B/row): wave per node, lane = 2 feats,
//      HW packed fp8->f32 convert ----
__global__ void k_aggregate(const unsigned char* __restrict__ src8, bf16* __restrict__ dst,
                            const int* __restrict__ row_ptr, const int* __restrict__ col_idx,
                            const float* __restrict__ inv_deg, int n) {
    int node = blockIdx.x * 4 + (threadIdx.x >> 6);
    int lane = threadIdx.x & 63;
    if (node >= n) return;
    int e0 = row_ptr[node], e1 = row_ptr[node + 1];
    const unsigned char* sp = src8 + (lane << 1);
    float f0 = 0.f, f1 = 0.f;
    int e = e0;
    for (; e + 7 < e1; e += 8) {
        uint32_t u0 = *(const uint16_t*)(sp + (size_t)col_idx[e] * 128);
        uint32_t u1 = *(const uint16_t*)(sp + (size_t)col_idx[e + 1] * 128);
        uint32_t u2 = *(const uint16_t*)(sp + (size_t)col_idx[e + 2] * 128);
        uint32_t u3 = *(const uint16_t*)(sp + (size_t)col_idx[e + 3] * 128);
        uint32_t u4 = *(const uint16_t*)(sp + (size_t)col_idx[e + 4] * 128);
        uint32_t u5 = *(const uint16_t*)(sp + (size_t)col_idx[e + 5] * 128);
        uint32_t u6 = *(const uint16_t*)(sp + (size_t)col_idx[e + 6] * 128);
        uint32_t u7 = *(const uint16_t*)(sp + (size_t)col_idx[e + 7] * 128);
        f32x2 p0 = __builtin_amdgcn_cvt_pk_f32_fp8(u0, false);
        f32x2 p1 = __builtin_amdgcn_cvt_pk_f32_fp8(u1, false);
        f32x2 p2 = __builtin_amdgcn_cvt_pk_f32_fp8(u2, false);
        f32x2 p3 = __builtin_amdgcn_cvt_pk_f32_fp8(u3, false);
        f32x2 p4 = __builtin_amdgcn_cvt_pk_f32_fp8(u4, false);
        f32x2 p5 = __builtin_amdgcn_cvt_pk_f32_fp8(u5, false);
        f32x2 p6 = __builtin_amdgcn_cvt_pk_f32_fp8(u6, false);
        f32x2 p7 = __builtin_amdgcn_cvt_pk_f32_fp8(u7, false);
        f0 += ((p0[0] + p1[0]) + (p2[0] + p3[0])) + ((p4[0] + p5[0]) + (p6[0] + p7[0]));
        f1 += ((p0[1] + p1[1]) + (p2[1] + p3[1])) + ((p4[1] + p5[1]) + (p6[1] + p7[1]));
    }
    for (; e < e1; ++e) {
        uint32_t u0 = *(const uint16_t*)(sp + (size_t)col_idx[e] * 128);
        f32x2 p0 = __builtin_amdgcn_cvt_pk_f32_fp8(u0, false);
        f0 += p0[0];
        f1 += p0[1];
    }
    float inv = inv_deg[node];
    bf16x2 o; o[0] = (bf16)(f0 * inv); o[1] = (bf16)(f1 * inv);
    *(bf16x2*)(dst + (size_t)node * 128 + (lane << 1)) = o;
}

// ---- MFMA GEMM: out[M x ncols] = [A1|A2] @ Bt^T (+ bias), fused BN stats ----
__global__ __launch_bounds__(256) void k_gemm(
    const bf16* __restrict__ A1, const bf16* __restrict__ A2, const bf16* __restrict__ Bt,
    const float* __restrict__ bias, float* __restrict__ outF,
    fp8* __restrict__ yl8, bf16* __restrict__ yrbf, float* __restrict__ stats,
    int M, int ncols, int ldc, int cps, int chunks, int ldb) {
    __shared__ __attribute__((aligned(16))) bf16 sA[4096];
    __shared__ __attribute__((aligned(16))) bf16 sB[4096];
    __shared__ float scol[128], scol2[128];
    const int tid = threadIdx.x;
    const int w = tid >> 6, l = tid & 63;
    const int q = l >> 4, r = l & 15;
    const int r0 = blockIdx.x * 128;
    if (tid < 128) { scol[tid] = 0.f; scol2[tid] = 0.f; }
    f32x4 acc[2][8];
    #pragma unroll
    for (int i = 0; i < 2; ++i)
        #pragma unroll
        for (int j = 0; j < 8; ++j) { acc[i][j][0] = 0.f; acc[i][j][1] = 0.f; acc[i][j][2] = 0.f; acc[i][j][3] = 0.f; }

    for (int c = 0; c < chunks; ++c) {
        const bf16* As = (c < cps) ? A1 : A2;
        const int ka = (c < cps ? c : c - cps) * 32;
        __syncthreads();
        #pragma unroll
        for (int i = 0; i < 2; ++i) {
            const int T = w * 2 + i;
            const bf16* ga = As + (size_t)(r0 + T * 16 + r) * 128 + ka + q * 8;
            const bf16* gb = Bt + (T * 16 + r) * ldb + c * 32 + q * 8;
            uint32_t la = (uint32_t)(uintptr_t)(&sA[T * 512]);
            uint32_t lb = (uint32_t)(uintptr_t)(&sB[T * 512]);
            __builtin_amdgcn_global_load_lds((AS1 uint32_t*)(uintptr_t)ga, (AS3 uint32_t*)la, 16, 0, 0);
            __builtin_amdgcn_global_load_lds((AS1 uint32_t*)(uintptr_t)gb, (AS3 uint32_t*)lb, 16, 0, 0);
        }
        __syncthreads();
        bf16x8 af0 = *(const bf16x8*)&sA[(w * 2 + 0) * 512 + q * 128 + r * 8];
        bf16x8 af1 = *(const bf16x8*)&sA[(w * 2 + 1) * 512 + q * 128 + r * 8];
        #pragma unroll
        for (int ct = 0; ct < 8; ++ct) {
            bf16x8 bv = *(const bf16x8*)&sB[ct * 512 + q * 128 + r * 8];
            acc[0][ct] = __builtin_amdgcn_mfma_f32_16x16x32_bf16(af0, bv, acc[0][ct], 0, 0, 0);
            acc[1][ct] = __builtin_amdgcn_mfma_f32_16x16x32_bf16(af1, bv, acc[1][ct], 0, 0, 0);
        }
    }
    if (yl8 == nullptr) {
        #pragma unroll
        for (int ct = 0; ct < 8; ++ct) {
            int col = ct * 16 + r;
            float bv = bias ? bias[col] : 0.f;
            float s_c = 0.f, q_c = 0.f;
            #pragma unroll
            for (int rt = 0; rt < 2; ++rt) {
                #pragma unroll
                for (int j = 0; j < 4; ++j) {
                    int row = r0 + w * 32 + rt * 16 + q * 4 + j;
                    if (row < M) {
                        float v = acc[rt][ct][j] + bv;
                        outF[(size_t)row * ldc + col] = v;
                        s_c += v; q_c += v * v;
                    }
                }
            }
            atomicAdd(&scol[col], s_c);
            atomicAdd(&scol2[col], q_c);
        }
        __syncthreads();
        if (tid < 128) {
            atomicAdd(&stats[tid], scol[tid]);
            atomicAdd(&stats[128 + tid], scol2[tid]);
        }
    } else {
        #pragma unroll
        for (int rt = 0; rt < 2; ++rt) {
            #pragma unroll
            for (int ct = 0; ct < 8; ++ct) {
                int col = ct * 16 + r;
                #pragma unroll
                for (int j = 0; j < 4; ++j) {
                    int row = r0 + w * 32 + rt * 16 + q * 4 + j;
                    if (row >= M) continue;
                    if (col < 47)      yl8[(size_t)row * 64 + col] = fp8(acc[rt][ct][j]);
                    else if (col < 94) yrbf[(size_t)row * 48 + (col - 47)] = (bf16)acc[rt][ct][j];
                }
            }
        }
    }
}

// ---- BN apply + ReLU -> bf16 (GEMM input) + fp8 (gather table) ----
__global__ void k_bn_apply(const float* __restrict__ h, const float* __restrict__ sums,
                           const float* __restrict__ gma, const float* __restrict__ bta,
                           bf16* __restrict__ out, unsigned char* __restrict__ out8, int n) {
    int g = blockIdx.x * blockDim.x + threadIdx.x;
    int row = g >> 6, c2 = g & 63;
    if (row >= n) return;
    int col = c2 << 1;
    float invn = 1.0f / (float)n;
    float mu0 = sums[col] * invn, mu1 = sums[col + 1] * invn;
    float v0 = sums[128 + col] * invn - mu0 * mu0;
    float v1 = sums[128 + col + 1] * invn - mu1 * mu1;
    float sc0 = gma[col] * rsqrtf(v0 + BN_EPS);
    float sc1 = gma[col + 1] * rsqrtf(v1 + BN_EPS);
    float sh0 = bta[col] - mu0 * sc0;
    float sh1 = bta[col + 1] - mu1 * sc1;
    float2 hv = *(const float2*)(h + (size_t)row * 128 + col);
    float r0 = fmaxf(hv.x * sc0 + sh0, 0.f);
    float r1 = fmaxf(hv.y * sc1 + sh1, 0.f);
    bf16x2 o; o[0] = (bf16)r0; o[1] = (bf16)r1;
    *(bf16x2*)(out + (size_t)row * 128 + col) = o;
    uchar2 o8; o8.x = fp8(r0).__x; o8.y = fp8(r1).__x;
    *(uchar2*)(out8 + (size_t)row * 128 + col) = o8;
}

// ---- final: gather-mean of yl (fp8, stride 64 = 1 line/edge, HW cvt) + yr + bl2,
//      log_softmax ----
__global__ void k_final(const unsigned char* __restrict__ yl, const bf16* __restrict__ yr,
                        const int* __restrict__ row_ptr, const int* __restrict__ col_idx,
                        const float* __restrict__ inv_deg, const float* __restrict__ bl2,
                        float* __restrict__ out, int n) {
    int node = blockIdx.x * 4 + (threadIdx.x >> 6);
    int c = threadIdx.x & 63;
    if (node >= n) return;
    int e0 = row_ptr[node], e1 = row_ptr[node + 1];
    bool valid = (c < 47);
    const unsigned char* ylc = yl + c;   // one 64B line per edge
    float acc = 0.f;
    int e = e0;
    for (; e + 7 < e1; e += 8) {
        uint32_t b0 = ylc[(size_t)col_idx[e] * 64];
        uint32_t b1 = ylc[(size_t)col_idx[e + 1] * 64];
        uint32_t b2 = ylc[(size_t)col_idx[e + 2] * 64];
        uint32_t b3 = ylc[(size_t)col_idx[e + 3] * 64];
        uint32_t b4 = ylc[(size_t)col_idx[e + 4] * 64];
        uint32_t b5 = ylc[(size_t)col_idx[e + 5] * 64];
        uint32_t b6 = ylc[(size_t)col_idx[e + 6] * 64];
        uint32_t b7 = ylc[(size_t)col_idx[e + 7] * 64];
        float v0 = __builtin_amdgcn_cvt_f32_fp8(b0, 0);
        float v1 = __builtin_amdgcn_cvt_f32_fp8(b1, 0);
        float v2 = __builtin_amdgcn_cvt_f32_fp8(b2, 0);
        float v3 = __builtin_amdgcn_cvt_f32_fp8(b3, 0);
        float v4 = __builtin_amdgcn_cvt_f32_fp8(b4, 0);
        float v5 = __builtin_amdgcn_cvt_f32_fp8(b5, 0);
        float v6 = __builtin_amdgcn_cvt_f32_fp8(b6, 0);
        float v7 = __builtin_amdgcn_cvt_f32_fp8(b7, 0);
        acc += ((v0 + v1) + (v2 + v3)) + ((v4 + v5) + (v6 + v7));
    }
    for (; e < e1; ++e) {
        uint32_t b0 = ylc[(size_t)col_idx[e] * 64];
        acc += __builtin_amdgcn_cvt_f32_fp8(b0, 0);
    }
    int cc = valid ? c : 0;
    float yv = (float)yr[(size_t)node * 48 + cc];
    float bv = bl2[cc];
    float val = valid ? (acc * inv_deg[node] + yv + bv) : -__builtin_inff();
    float m = val;
    #pragma unroll
    for (int o = 32; o > 0; o >>= 1) m = fmaxf(m, __shfl_xor(m, o, 64));
    float ex = valid ? expf(val - m) : 0.f;
    float sum = ex;
    #pragma unroll
    for (int o = 32; o > 0; o >>= 1) sum += __shfl_xor(sum, o, 64);
    if (valid) out[(size_t)node * 47 + c] = val - m - logf(sum);
}

extern "C" void kernel_launch(void* const* d_in, const int* in_sizes, int n_in,
                              void* d_out, int out_size, void* d_ws, size_t ws_size,
                              hipStream_t stream) {
    const float* x   = (const float*)d_in[0];
    const int*   ei  = (const int*)d_in[1];
    const float* Wl0 = (const float*)d_in[2];
    const float* bl0 = (const float*)d_in[3];
    const float* Wr0 = (const float*)d_in[4];
    const float* g0  = (const float*)d_in[5];
    const float* be0 = (const float*)d_in[6];
    const float* Wl1 = (const float*)d_in[7];
    const float* bl1 = (const float*)d_in[8];
    const float* Wr1 = (const float*)d_in[9];
    const float* g1  = (const float*)d_in[10];
    const float* be1 = (const float*)d_in[11];
    const float* Wl2 = (const float*)d_in[12];
    const float* bl2 = (const float*)d_in[13];
    const float* Wr2 = (const float*)d_in[14];
    float* out = (float*)d_out;

    const int N  = in_sizes[0] / 128;
    const int E  = in_sizes[1] / 2;
    const int NP = ((N + 127) / 128) * 128;
    const int NBKT = (N + BKT_NODES - 1) / BKT_NODES;

    char* p = (char*)d_ws;
    size_t off = 0;
    auto alloc = [&](size_t b) { char* r = p + off; off += (b + 255) & ~(size_t)255; return r; };
    // zero-init region (one memset): bfill, bnsum, btot
    int*   bfill   = (int*)alloc(1024 * 4);
    float* bnsum   = (float*)alloc(512 * 4);
    int*   btot    = (int*)alloc(512 * 4);
    size_t zero_span = off;
    int*   row_ptr = (int*)alloc((size_t)(N + 1) * 4);
    float* invd    = (float*)alloc((size_t)N * 4);
    int*   col_idx = (int*)alloc((size_t)E * 4);
    uint32_t* pair_buf = (uint32_t*)alloc((size_t)E * 4);
    int*   bbase   = (int*)alloc(1024 * 4);
    bf16*  x_bf    = (bf16*)alloc((size_t)NP * 128 * 2);
    bf16*  aggbf   = (bf16*)alloc((size_t)NP * 128 * 2);
    bf16*  hbf     = (bf16*)alloc((size_t)NP * 128 * 2);
    unsigned char* h8 = (unsigned char*)alloc((size_t)NP * 128);
    float* bufF    = (float*)alloc((size_t)NP * 128 * 4 + 256);
    bf16*  Bt0     = (bf16*)alloc(128 * 256 * 2);
    bf16*  Bt1     = (bf16*)alloc(128 * 256 * 2);
    bf16*  Bt2     = (bf16*)alloc(128 * 128 * 2);
    // aliases into bufF (sequentially dead/live): x8 (pre-GEMM0), yl8/yrbf (post-BN1)
    unsigned char* x8 = (unsigned char*)bufF;
    fp8*   yl8  = (fp8*)bufF;
    bf16*  yrbf = (bf16*)((char*)bufF + (size_t)NP * 64);

    hipMemsetAsync(bfill, 0, zero_span, stream);

    int n4 = N * 128 / 4;
    k_setup<<<(n4 + 255) / 256, 256, 0, stream>>>(x, x_bf, x8, n4, ei, btot, E, NBKT,
                                                  Wl0, Wr0, Wl1, Wr1, Wl2, Wr2, Bt0, Bt1, Bt2);
    k_bscan<<<1, 512, 0, stream>>>(btot, bbase, row_ptr, N, E, NBKT);
    k_bin<<<(E + TILE_E - 1) / TILE_E, 256, 0, stream>>>(ei, bbase, bfill, pair_buf, E, NBKT);
    k_fill2<<<NBKT, 256, 0, stream>>>(pair_buf, bbase, row_ptr, invd, col_idx, N);

    int aggBlocks  = (N + 3) / 4;
    int gemmBlocks = NP / 128;

    // Layer 0
    k_aggregate<<<aggBlocks, 256, 0, stream>>>(x8, aggbf, row_ptr, col_idx, invd, N);
    k_gemm<<<gemmBlocks, 256, 0, stream>>>(aggbf, x_bf, Bt0, bl0, bufF, nullptr, nullptr, bnsum, N, 128, 128, 4, 8, 256);
    k_bn_apply<<<(N * 64 + 255) / 256, 256, 0, stream>>>(bufF, bnsum, g0, be0, hbf, h8, N);
    // Layer 1
    k_aggregate<<<aggBlocks, 256, 0, stream>>>(h8, aggbf, row_ptr, col_idx, invd, N);
    k_gemm<<<gemmBlocks, 256, 0, stream>>>(aggbf, hbf, Bt1, bl1, bufF, nullptr, nullptr, bnsum + 256, N, 128, 128, 4, 8, 256);
    k_bn_apply<<<(N * 64 + 255) / 256, 256, 0, stream>>>(bufF, bnsum + 256, g1, be1, hbf, h8, N);
    // Layer 2: project to yl (fp8, stride 64) / yr (bf16), then gather + log_softmax
    k_gemm<<<gemmBlocks, 256, 0, stream>>>(hbf, hbf, Bt2, nullptr, nullptr, yl8, yrbf, nullptr, N, 94, 96, 4, 4, 128);
    k_final<<<aggBlocks, 256, 0, stream>>>((const unsigned char*)yl8, yrbf, row_ptr, col_idx, invd, bl2, out, N);
}

// Round 9
// 553.983 us; speedup vs baseline: 1.5504x; 1.0278x over previous
//
#include <hip/hip_runtime.h>
#include <hip/hip_fp8.h>
#include <stdint.h>

#define AS1 __attribute__((address_space(1)))
#define AS3 __attribute__((address_space(3)))

typedef __bf16 bf16;
typedef __bf16 bf16x2 __attribute__((ext_vector_type(2)));
typedef __bf16 bf16x4v __attribute__((ext_vector_type(4)));
typedef __bf16 bf16x8 __attribute__((ext_vector_type(8)));
typedef float f32x4 __attribute__((ext_vector_type(4)));
typedef float f32x2 __attribute__((ext_vector_type(2)));
typedef __hip_fp8_e4m3 fp8;

#define BN_EPS 1e-5f
#define BKT_SHIFT 8              // 256 nodes per bucket
#define BKT_NODES 256
#define TILE_E 2048              // edges per binning block

// ---- fused setup: weight cvt+transpose, x fp32 -> bf16 + fp8, bucket count ----
__global__ void k_setup(const float* __restrict__ x, bf16* __restrict__ x_bf,
                        unsigned char* __restrict__ x8, int n4,
                        const int* __restrict__ ei, int* __restrict__ btot, int E, int nbkt,
                        const float* __restrict__ Wl0, const float* __restrict__ Wr0,
                        const float* __restrict__ Wl1, const float* __restrict__ Wr1,
                        const float* __restrict__ Wl2, const float* __restrict__ Wr2,
                        bf16* __restrict__ Bt0, bf16* __restrict__ Bt1, bf16* __restrict__ Bt2) {
    __shared__ int hist[512];
    const int tid = threadIdx.x;
    int g = blockIdx.x * 256 + tid;
    if (g < n4) {
        float4 v = ((const float4*)x)[g];
        bf16x4v o; o[0] = (bf16)v.x; o[1] = (bf16)v.y; o[2] = (bf16)v.z; o[3] = (bf16)v.w;
        ((bf16x4v*)x_bf)[g] = o;
        uchar4 o8;
        o8.x = fp8(v.x).__x; o8.y = fp8(v.y).__x; o8.z = fp8(v.z).__x; o8.w = fp8(v.w).__x;
        ((uchar4*)x8)[g] = o8;
    }
    if (blockIdx.x < 128) {
        int idx = g;                 // 32768 threads: c in [0,128), k in [0,256)
        int c = idx >> 8, k = idx & 255;
        float v0 = (k < 128) ? Wl0[k * 128 + c] : Wr0[(k - 128) * 128 + c];
        Bt0[c * 256 + k] = (bf16)v0;
        float v1 = (k < 128) ? Wl1[k * 128 + c] : Wr1[(k - 128) * 128 + c];
        Bt1[c * 256 + k] = (bf16)v1;
        if (k < 128) {
            float v2 = 0.f;
            if (c < 47)      v2 = Wl2[k * 47 + c];
            else if (c < 94) v2 = Wr2[k * 47 + (c - 47)];
            Bt2[c * 128 + k] = (bf16)v2;
        }
    }
    // bucket histogram for blocks [0, ceil(E/4096))
    int nbinb = (E + 4095) / 4096;
    if (blockIdx.x < nbinb) {
        hist[tid] = 0; hist[tid + 256] = 0;
        __syncthreads();
        const int e0 = blockIdx.x * 4096;
        #pragma unroll
        for (int k = 0; k < 4; ++k) {
            int i4 = (e0 >> 2) + k * 256 + tid;
            if (i4 * 4 + 3 < E) {
                int4 d4 = ((const int4*)(ei + E))[i4];
                atomicAdd(&hist[d4.x >> BKT_SHIFT], 1);
                atomicAdd(&hist[d4.y >> BKT_SHIFT], 1);
                atomicAdd(&hist[d4.z >> BKT_SHIFT], 1);
                atomicAdd(&hist[d4.w >> BKT_SHIFT], 1);
            } else {
                for (int e = i4 * 4; e < min(E, i4 * 4 + 4); ++e)
                    atomicAdd(&hist[ei[E + e] >> BKT_SHIFT], 1);
            }
        }
        __syncthreads();
        for (int b = tid; b < nbkt; b += 256)
            if (hist[b]) atomicAdd(&btot[b], hist[b]);
    }
}

// In-block exclusive scan of btot[0..512) into sb[0..512], sb[512]=total.
// Requires 256 threads; uses caller-provided LDS sb[513], wsum[8]. One
// __syncthreads-bracketed sequence; caller must sync before reading sb? No —
// final __syncthreads included.
__device__ __forceinline__ void scan_btot(const int* __restrict__ btot, int nbkt,
                                          int* sb, int* wsum) {
    const int tid = threadIdx.x, lane = tid & 63, wid = tid >> 6;
    int a = (tid < nbkt) ? btot[tid] : 0;
    int b2 = (tid + 256 < nbkt) ? btot[tid + 256] : 0;
    int ia = a, ib = b2;
    #pragma unroll
    for (int d = 1; d < 64; d <<= 1) {
        int t1 = __shfl_up(ia, d, 64);
        int t2 = __shfl_up(ib, d, 64);
        if (lane >= d) { ia += t1; ib += t2; }
    }
    if (lane == 63) { wsum[wid] = ia; wsum[4 + wid] = ib; }
    __syncthreads();
    if (tid == 0) {
        int c = 0;
        #pragma unroll
        for (int i = 0; i < 8; ++i) { int t = wsum[i]; wsum[i] = c; c += t; }
    }
    __syncthreads();
    sb[tid] = ia - a + wsum[wid];
    sb[tid + 256] = ib - b2 + wsum[4 + wid];
    if (tid == 255) sb[512] = ib + wsum[7];
    __syncthreads();
}

// ---- binning pass: in-block bbase scan -> histogram -> claim -> ranked write ----
// pair = (src << 8) | (dst & 255); bucket = dst >> 8.
__global__ __launch_bounds__(256) void k_bin(const int* __restrict__ ei,
                                             const int* __restrict__ btot,
                                             int* __restrict__ bfill,
                                             uint32_t* __restrict__ pair_buf,
                                             int E, int nbkt) {
    __shared__ int hist[512], gbase[512], hcur[512];
    __shared__ int sb[513], wsum[8];
    const int tid = threadIdx.x;
    const int e0 = blockIdx.x * TILE_E;
    hist[tid] = 0; hist[tid + 256] = 0;
    scan_btot(btot, nbkt, sb, wsum);   // includes syncs; hist zeroed before first sync

    int dreg[TILE_E / 256];
    #pragma unroll
    for (int k = 0; k < TILE_E / 256; ++k) {
        int e = e0 + k * 256 + tid;
        int d = (e < E) ? ei[E + e] : -1;
        dreg[k] = d;
        if (d >= 0) atomicAdd(&hist[d >> BKT_SHIFT], 1);
    }
    __syncthreads();

    for (int b = tid; b < nbkt; b += 256) {
        int h = hist[b];
        int g = (h > 0) ? atomicAdd(&bfill[b], h) : 0;
        gbase[b] = sb[b] + g;
        hcur[b] = 0;
    }
    __syncthreads();

    #pragma unroll
    for (int k = 0; k < TILE_E / 256; ++k) {
        int d = dreg[k];
        if (d >= 0) {
            int e = e0 + k * 256 + tid;
            int s = ei[e];
            int b = d >> BKT_SHIFT;
            int r = atomicAdd(&hcur[b], 1);
            pair_buf[(size_t)gbase[b] + r] =
                ((uint32_t)s << BKT_SHIFT) | (uint32_t)(d & (BKT_NODES - 1));
        }
    }
}

// ---- fill: one block per bucket. In-block bbase scan, local deg hist -> scan ->
//      row_ptr/inv_deg, then rank-scatter col_idx. ----
__global__ __launch_bounds__(256) void k_fill2(const uint32_t* __restrict__ pair_buf,
                                               const int* __restrict__ btot,
                                               int* __restrict__ row_ptr,
                                               float* __restrict__ inv_deg,
                                               int* __restrict__ col_idx,
                                               int n, int E, int nbkt) {
    __shared__ int hist[256], excl[256], hcur[256], wsum4[4];
    __shared__ int sb[513], wsum[8];
    const int b = blockIdx.x;
    const int tid = threadIdx.x, lane = tid & 63, wid = tid >> 6;
    const int n0 = b << BKT_SHIFT;
    hist[tid] = 0; hcur[tid] = 0;
    scan_btot(btot, nbkt, sb, wsum);
    const int s = sb[b], e = sb[b + 1];
    for (int i = s + tid; i < e; i += 256)
        atomicAdd(&hist[pair_buf[i] & (BKT_NODES - 1)], 1);
    __syncthreads();
    int v = hist[tid];
    int incl = v;
    #pragma unroll
    for (int d = 1; d < 64; d <<= 1) {
        int t = __shfl_up(incl, d, 64);
        if (lane >= d) incl += t;
    }
    if (lane == 63) wsum4[wid] = incl;
    __syncthreads();
    if (tid == 0) {
        int c = 0;
        #pragma unroll
        for (int i = 0; i < 4; ++i) { int t = wsum4[i]; wsum4[i] = c; c += t; }
    }
    __syncthreads();
    int ex = incl - v + wsum4[wid];
    excl[tid] = ex;
    int node = n0 + tid;
    if (node < n) {
        row_ptr[node] = s + ex;
        inv_deg[node] = 1.0f / (float)(v > 1 ? v : 1);
    }
    if (b == (int)gridDim.x - 1 && tid == 0) row_ptr[n] = E;
    __syncthreads();
    for (int i = s + tid; i < e; i += 256) {
        uint32_t pk = pair_buf[i];
        int dl = pk & (BKT_NODES - 1);
        int r = atomicAdd(&hcur[dl], 1);
        col_idx[s + excl[dl] + r] = (int)(pk >> BKT_SHIFT);
    }
}

// ---- mean-aggregate from fp8 table (128 B/row): wave per node, lane = 2 feats,
//      int4 index loads + HW packed fp8->f32 ----
__global__ void k_aggregate(const unsigned char* __restrict__ src8, bf16* __restrict__ dst,
                            const int* __restrict__ row_ptr, const int* __restrict__ col_idx,
                            const float* __restrict__ inv_deg, int n) {
    int node = blockIdx.x * 4 + (threadIdx.x >> 6);
    int lane = threadIdx.x & 63;
    if (node >= n) return;
    int e0 = row_ptr[node], e1 = row_ptr[node + 1];
    float inv = inv_deg[node];
    const unsigned char* sp = src8 + (lane << 1);
    float f0 = 0.f, f1 = 0.f;
    int e = e0;
    // align to 4
    for (; e < e1 && (e & 3); ++e) {
        uint32_t u = *(const uint16_t*)(sp + (size_t)col_idx[e] * 128);
        f32x2 p = __builtin_amdgcn_cvt_pk_f32_fp8(u, false);
        f0 += p[0]; f1 += p[1];
    }
    for (; e + 7 < e1; e += 8) {
        int4 i0 = *(const int4*)(col_idx + e);
        int4 i1 = *(const int4*)(col_idx + e + 4);
        uint32_t u0 = *(const uint16_t*)(sp + (size_t)i0.x * 128);
        uint32_t u1 = *(const uint16_t*)(sp + (size_t)i0.y * 128);
        uint32_t u2 = *(const uint16_t*)(sp + (size_t)i0.z * 128);
        uint32_t u3 = *(const uint16_t*)(sp + (size_t)i0.w * 128);
        uint32_t u4 = *(const uint16_t*)(sp + (size_t)i1.x * 128);
        uint32_t u5 = *(const uint16_t*)(sp + (size_t)i1.y * 128);
        uint32_t u6 = *(const uint16_t*)(sp + (size_t)i1.z * 128);
        uint32_t u7 = *(const uint16_t*)(sp + (size_t)i1.w * 128);
        f32x2 p0 = __builtin_amdgcn_cvt_pk_f32_fp8(u0, false);
        f32x2 p1 = __builtin_amdgcn_cvt_pk_f32_fp8(u1, false);
        f32x2 p2 = __builtin_amdgcn_cvt_pk_f32_fp8(u2, false);
        f32x2 p3 = __builtin_amdgcn_cvt_pk_f32_fp8(u3, false);
        f32x2 p4 = __builtin_amdgcn_cvt_pk_f32_fp8(u4, false);
        f32x2 p5 = __builtin_amdgcn_cvt_pk_f32_fp8(u5, false);
        f32x2 p6 = __builtin_amdgcn_cvt_pk_f32_fp8(u6, false);
        f32x2 p7 = __builtin_amdgcn_cvt_pk_f32_fp8(u7, false);
        f0 += ((p0[0] + p1[0]) + (p2[0] + p3[0])) + ((p4[0] + p5[0]) + (p6[0] + p7[0]));
        f1 += ((p0[1] + p1[1]) + (p2[1] + p3[1])) + ((p4[1] + p5[1]) + (p6[1] + p7[1]));
    }
    if (e + 3 < e1) {
        int4 i0 = *(const int4*)(col_idx + e);
        uint32_t u0 = *(const uint16_t*)(sp + (size_t)i0.x * 128);
        uint32_t u1 = *(const uint16_t*)(sp + (size_t)i0.y * 128);
        uint32_t u2 = *(const uint16_t*)(sp + (size_t)i0.z * 128);
        uint32_t u3 = *(const uint16_t*)(sp + (size_t)i0.w * 128);
        f32x2 p0 = __builtin_amdgcn_cvt_pk_f32_fp8(u0, false);
        f32x2 p1 = __builtin_amdgcn_cvt_pk_f32_fp8(u1, false);
        f32x2 p2 = __builtin_amdgcn_cvt_pk_f32_fp8(u2, false);
        f32x2 p3 = __builtin_amdgcn_cvt_pk_f32_fp8(u3, false);
        f0 += (p0[0] + p1[0]) + (p2[0] + p3[0]);
        f1 += (p0[1] + p1[1]) + (p2[1] + p3[1]);
        e += 4;
    }
    for (; e < e1; ++e) {
        uint32_t u = *(const uint16_t*)(sp + (size_t)col_idx[e] * 128);
        f32x2 p = __builtin_amdgcn_cvt_pk_f32_fp8(u, false);
        f0 += p[0]; f1 += p[1];
    }
    bf16x2 o; o[0] = (bf16)(f0 * inv); o[1] = (bf16)(f1 * inv);
    *(bf16x2*)(dst + (size_t)node * 128 + (lane << 1)) = o;
}

// ---- MFMA GEMM: out[M x ncols] = [A1|A2] @ Bt^T (+ bias), fused BN stats ----
__global__ __launch_bounds__(256) void k_gemm(
    const bf16* __restrict__ A1, const bf16* __restrict__ A2, const bf16* __restrict__ Bt,
    const float* __restrict__ bias, float* __restrict__ outF,
    fp8* __restrict__ yl8, bf16* __restrict__ yrbf, float* __restrict__ stats,
    int M, int ncols, int ldc, int cps, int chunks, int ldb) {
    __shared__ __attribute__((aligned(16))) bf16 sA[4096];
    __shared__ __attribute__((aligned(16))) bf16 sB[4096];
    __shared__ float scol[128], scol2[128];
    const int tid = threadIdx.x;
    const int w = tid >> 6, l = tid & 63;
    const int q = l >> 4, r = l & 15;
    const int r0 = blockIdx.x * 128;
    if (tid < 128) { scol[tid] = 0.f; scol2[tid] = 0.f; }
    f32x4 acc[2][8];
    #pragma unroll
    for (int i = 0; i < 2; ++i)
        #pragma unroll
        for (int j = 0; j < 8; ++j) { acc[i][j][0] = 0.f; acc[i][j][1] = 0.f; acc[i][j][2] = 0.f; acc[i][j][3] = 0.f; }

    for (int c = 0; c < chunks; ++c) {
        const bf16* As = (c < cps) ? A1 : A2;
        const int ka = (c < cps ? c : c - cps) * 32;
        __syncthreads();
        #pragma unroll
        for (int i = 0; i < 2; ++i) {
            const int T = w * 2 + i;
            const bf16* ga = As + (size_t)(r0 + T * 16 + r) * 128 + ka + q * 8;
            const bf16* gb = Bt + (T * 16 + r) * ldb + c * 32 + q * 8;
            uint32_t la = (uint32_t)(uintptr_t)(&sA[T * 512]);
            uint32_t lb = (uint32_t)(uintptr_t)(&sB[T * 512]);
            __builtin_amdgcn_global_load_lds((AS1 uint32_t*)(uintptr_t)ga, (AS3 uint32_t*)la, 16, 0, 0);
            __builtin_amdgcn_global_load_lds((AS1 uint32_t*)(uintptr_t)gb, (AS3 uint32_t*)lb, 16, 0, 0);
        }
        __syncthreads();
        bf16x8 af0 = *(const bf16x8*)&sA[(w * 2 + 0) * 512 + q * 128 + r * 8];
        bf16x8 af1 = *(const bf16x8*)&sA[(w * 2 + 1) * 512 + q * 128 + r * 8];
        #pragma unroll
        for (int ct = 0; ct < 8; ++ct) {
            bf16x8 bv = *(const bf16x8*)&sB[ct * 512 + q * 128 + r * 8];
            acc[0][ct] = __builtin_amdgcn_mfma_f32_16x16x32_bf16(af0, bv, acc[0][ct], 0, 0, 0);
            acc[1][ct] = __builtin_amdgcn_mfma_f32_16x16x32_bf16(af1, bv, acc[1][ct], 0, 0, 0);
        }
    }
    if (yl8 == nullptr) {
        #pragma unroll
        for (int ct = 0; ct < 8; ++ct) {
            int col = ct * 16 + r;
            float bv = bias ? bias[col] : 0.f;
            float s_c = 0.f, q_c = 0.f;
            #pragma unroll
            for (int rt = 0; rt < 2; ++rt) {
                #pragma unroll
                for (int j = 0; j < 4; ++j) {
                    int row = r0 + w * 32 + rt * 16 + q * 4 + j;
                    if (row < M) {
                        float v = acc[rt][ct][j] + bv;
                        outF[(size_t)row * ldc + col] = v;
                        s_c += v; q_c += v * v;
                    }
                }
            }
            atomicAdd(&scol[col], s_c);
            atomicAdd(&scol2[col], q_c);
        }
        __syncthreads();
        if (tid < 128) {
            atomicAdd(&stats[tid], scol[tid]);
            atomicAdd(&stats[128 + tid], scol2[tid]);
        }
    } else {
        #pragma unroll
        for (int rt = 0; rt < 2; ++rt) {
            #pragma unroll
            for (int ct = 0; ct < 8; ++ct) {
                int col = ct * 16 + r;
                #pragma unroll
                for (int j = 0; j < 4; ++j) {
                    int row = r0 + w * 32 + rt * 16 + q * 4 + j;
                    if (row >= M) continue;
                    if (col < 47)      yl8[(size_t)row * 64 + col] = fp8(acc[rt][ct][j]);
                    else if (col < 94) yrbf[(size_t)row * 48 + (col - 47)] = (bf16)acc[rt][ct][j];
                }
            }
        }
    }
}

// ---- BN apply + ReLU -> bf16 (GEMM input) + fp8 (gather table) ----
__global__ void k_bn_apply(const float* __restrict__ h, const float* __restrict__ sums,
                           const float* __restrict__ gma, const float* __restrict__ bta,
                           bf16* __restrict__ out, unsigned char* __restrict__ out8, int n) {
    int g = blockIdx.x * blockDim.x + threadIdx.x;
    int row = g >> 6, c2 = g & 63;
    if (row >= n) return;
    int col = c2 << 1;
    float invn = 1.0f / (float)n;
    float mu0 = sums[col] * invn, mu1 = sums[col + 1] * invn;
    float v0 = sums[128 + col] * invn - mu0 * mu0;
    float v1 = sums[128 + col + 1] * invn - mu1 * mu1;
    float sc0 = gma[col] * rsqrtf(v0 + BN_EPS);
    float sc1 = gma[col + 1] * rsqrtf(v1 + BN_EPS);
    float sh0 = bta[col] - mu0 * sc0;
    float sh1 = bta[col + 1] - mu1 * sc1;
    float2 hv = *(const float2*)(h + (size_t)row * 128 + col);
    float r0 = fmaxf(hv.x * sc0 + sh0, 0.f);
    float r1 = fmaxf(hv.y * sc1 + sh1, 0.f);
    bf16x2 o; o[0] = (bf16)r0; o[1] = (bf16)r1;
    *(bf16x2*)(out + (size_t)row * 128 + col) = o;
    uchar2 o8; o8.x = fp8(r0).__x; o8.y = fp8(r1).__x;
    *(uchar2*)(out8 + (size_t)row * 128 + col) = o8;
}

// ---- final: gather-mean of yl (fp8, stride 64 = 1 line/edge) + yr + bl2,
//      log_softmax (fast exp/log, int4 index loads) ----
__global__ void k_final(const unsigned char* __restrict__ yl, const bf16* __restrict__ yr,
                        const int* __restrict__ row_ptr, const int* __restrict__ col_idx,
                        const float* __restrict__ inv_deg, const float* __restrict__ bl2,
                        float* __restrict__ out, int n) {
    int node = blockIdx.x * 4 + (threadIdx.x >> 6);
    int c = threadIdx.x & 63;
    if (node >= n) return;
    int e0 = row_ptr[node], e1 = row_ptr[node + 1];
    float inv = inv_deg[node];
    bool valid = (c < 47);
    const unsigned char* ylc = yl + c;   // one 64B line per edge
    float acc = 0.f;
    int e = e0;
    for (; e < e1 && (e & 3); ++e)
        acc += __builtin_amdgcn_cvt_f32_fp8((uint32_t)ylc[(size_t)col_idx[e] * 64], 0);
    for (; e + 7 < e1; e += 8) {
        int4 i0 = *(const int4*)(col_idx + e);
        int4 i1 = *(const int4*)(col_idx + e + 4);
        uint32_t b0 = ylc[(size_t)i0.x * 64];
        uint32_t b1 = ylc[(size_t)i0.y * 64];
        uint32_t b2 = ylc[(size_t)i0.z * 64];
        uint32_t b3 = ylc[(size_t)i0.w * 64];
        uint32_t b4 = ylc[(size_t)i1.x * 64];
        uint32_t b5 = ylc[(size_t)i1.y * 64];
        uint32_t b6 = ylc[(size_t)i1.z * 64];
        uint32_t b7 = ylc[(size_t)i1.w * 64];
        float v0 = __builtin_amdgcn_cvt_f32_fp8(b0, 0);
        float v1 = __builtin_amdgcn_cvt_f32_fp8(b1, 0);
        float v2 = __builtin_amdgcn_cvt_f32_fp8(b2, 0);
        float v3 = __builtin_amdgcn_cvt_f32_fp8(b3, 0);
        float v4 = __builtin_amdgcn_cvt_f32_fp8(b4, 0);
        float v5 = __builtin_amdgcn_cvt_f32_fp8(b5, 0);
        float v6 = __builtin_amdgcn_cvt_f32_fp8(b6, 0);
        float v7 = __builtin_amdgcn_cvt_f32_fp8(b7, 0);
        acc += ((v0 + v1) + (v2 + v3)) + ((v4 + v5) + (v6 + v7));
    }
    if (e + 3 < e1) {
        int4 i0 = *(const int4*)(col_idx + e);
        uint32_t b0 = ylc[(size_t)i0.x * 64];
        uint32_t b1 = ylc[(size_t)i0.y * 64];
        uint32_t b2 = ylc[(size_t)i0.z * 64];
        uint32_t b3 = ylc[(size_t)i0.w * 64];
        acc += (__builtin_amdgcn_cvt_f32_fp8(b0, 0) + __builtin_amdgcn_cvt_f32_fp8(b1, 0)) +
               (__builtin_amdgcn_cvt_f32_fp8(b2, 0) + __builtin_amdgcn_cvt_f32_fp8(b3, 0));
        e += 4;
    }
    for (; e < e1; ++e)
        acc += __builtin_amdgcn_cvt_f32_fp8((uint32_t)ylc[(size_t)col_idx[e] * 64], 0);
    int cc = valid ? c : 0;
    float yv = (float)yr[(size_t)node * 48 + cc];
    float bv = bl2[cc];
    float val = valid ? (acc * inv + yv + bv) : -__builtin_inff();
    float m = val;
    #pragma unroll
    for (int o = 32; o > 0; o >>= 1) m = fmaxf(m, __shfl_xor(m, o, 64));
    float ex = valid ? __expf(val - m) : 0.f;
    float sum = ex;
    #pragma unroll
    for (int o = 32; o > 0; o >>= 1) sum += __shfl_xor(sum, o, 64);
    if (valid) out[(size_t)node * 47 + c] = val - m - __logf(sum);
}

extern "C" void kernel_launch(void* const* d_in, const int* in_sizes, int n_in,
                              void* d_out, int out_size, void* d_ws, size_t ws_size,
                              hipStream_t stream) {
    const float* x   = (const float*)d_in[0];
    const int*   ei  = (const int*)d_in[1];
    const float* Wl0 = (const float*)d_in[2];
    const float* bl0 = (const float*)d_in[3];
    const float* Wr0 = (const float*)d_in[4];
    const float* g0  = (const float*)d_in[5];
    const float* be0 = (const float*)d_in[6];
    const float* Wl1 = (const float*)d_in[7];
    const float* bl1 = (const float*)d_in[8];
    const float* Wr1 = (const float*)d_in[9];
    const float* g1  = (const float*)d_in[10];
    const float* be1 = (const float*)d_in[11];
    const float* Wl2 = (const float*)d_in[12];
    const float* bl2 = (const float*)d_in[13];
    const float* Wr2 = (const float*)d_in[14];
    float* out = (float*)d_out;

    const int N  = in_sizes[0] / 128;
    const int E  = in_sizes[1] / 2;
    const int NP = ((N + 127) / 128) * 128;
    const int NBKT = (N + BKT_NODES - 1) / BKT_NODES;

    char* p = (char*)d_ws;
    size_t off = 0;
    auto alloc = [&](size_t b) { char* r = p + off; off += (b + 255) & ~(size_t)255; return r; };
    // zero-init region (one memset): bfill, bnsum, btot
    int*   bfill   = (int*)alloc(1024 * 4);
    float* bnsum   = (float*)alloc(512 * 4);
    int*   btot    = (int*)alloc(512 * 4);
    size_t zero_span = off;
    int*   row_ptr = (int*)alloc((size_t)(N + 1) * 4);
    float* invd    = (float*)alloc((size_t)N * 4);
    int*   col_idx = (int*)alloc((size_t)E * 4);
    uint32_t* pair_buf = (uint32_t*)alloc((size_t)E * 4);
    bf16*  x_bf    = (bf16*)alloc((size_t)NP * 128 * 2);
    bf16*  aggbf   = (bf16*)alloc((size_t)NP * 128 * 2);
    bf16*  hbf     = (bf16*)alloc((size_t)NP * 128 * 2);
    unsigned char* h8 = (unsigned char*)alloc((size_t)NP * 128);
    float* bufF    = (float*)alloc((size_t)NP * 128 * 4 + 256);
    bf16*  Bt0     = (bf16*)alloc(128 * 256 * 2);
    bf16*  Bt1     = (bf16*)alloc(128 * 256 * 2);
    bf16*  Bt2     = (bf16*)alloc(128 * 128 * 2);
    // aliases into bufF (sequentially dead/live): x8 (pre-GEMM0), yl8/yrbf (post-BN1)
    unsigned char* x8 = (unsigned char*)bufF;
    fp8*   yl8  = (fp8*)bufF;
    bf16*  yrbf = (bf16*)((char*)bufF + (size_t)NP * 64);

    hipMemsetAsync(bfill, 0, zero_span, stream);

    int n4 = N * 128 / 4;
    k_setup<<<(n4 + 255) / 256, 256, 0, stream>>>(x, x_bf, x8, n4, ei, btot, E, NBKT,
                                                  Wl0, Wr0, Wl1, Wr1, Wl2, Wr2, Bt0, Bt1, Bt2);
    k_bin<<<(E + TILE_E - 1) / TILE_E, 256, 0, stream>>>(ei, btot, bfill, pair_buf, E, NBKT);
    k_fill2<<<NBKT, 256, 0, stream>>>(pair_buf, btot, row_ptr, invd, col_idx, N, E, NBKT);

    int aggBlocks  = (N + 3) / 4;
    int gemmBlocks = NP / 128;

    // Layer 0
    k_aggregate<<<aggBlocks, 256, 0, stream>>>(x8, aggbf, row_ptr, col_idx, invd, N);
    k_gemm<<<gemmBlocks, 256, 0, stream>>>(aggbf, x_bf, Bt0, bl0, bufF, nullptr, nullptr, bnsum, N, 128, 128, 4, 8, 256);
    k_bn_apply<<<(N * 64 + 255) / 256, 256, 0, stream>>>(bufF, bnsum, g0, be0, hbf, h8, N);
    // Layer 1
    k_aggregate<<<aggBlocks, 256, 0, stream>>>(h8, aggbf, row_ptr, col_idx, invd, N);
    k_gemm<<<gemmBlocks, 256, 0, stream>>>(aggbf, hbf, Bt1, bl1, bufF, nullptr, nullptr, bnsum + 256, N, 128, 128, 4, 8, 256);
    k_bn_apply<<<(N * 64 + 255) / 256, 256, 0, stream>>>(bufF, bnsum + 256, g1, be1, hbf, h8, N);
    // Layer 2: project to yl (fp8, stride 64) / yr (bf16), then gather + log_softmax
    k_gemm<<<gemmBlocks, 256, 0, stream>>>(hbf, hbf, Bt2, nullptr, nullptr, yl8, yrbf, nullptr, N, 94, 96, 4, 4, 128);
    k_final<<<aggBlocks, 256, 0, stream>>>((const unsigned char*)yl8, yrbf, row_ptr, col_idx, invd, bl2, out, N);
}